// Round 2
// baseline (14650.392 us; speedup 1.0000x reference)
//
#include <hip/hip_runtime.h>
#include <hip/hip_bf16.h>

typedef __bf16 bf16;
typedef __bf16 bf16x8 __attribute__((ext_vector_type(8)));
typedef float floatx16 __attribute__((ext_vector_type(16)));

#define TSEQ 512
#define HID 256

__device__ __forceinline__ float sigm(float x){ return 1.0f/(1.0f + __expf(-x)); }
__device__ __forceinline__ float tanh_fast(float x){
    float e = __expf(2.0f*x);
    return 1.0f - 2.0f/(e + 1.0f);   // correct limits at +-inf
}

// fp32 -> bf16 converter (for fc1 weight)
__global__ __launch_bounds__(256, 4)
void f2b_kernel(const float* __restrict__ in, bf16* __restrict__ out, int n)
{
    int i = blockIdx.x*256 + threadIdx.x;
    if (i < n) out[i] = (bf16)in[i];
}

// ---------------------------------------------------------------------------
// Persistent BiLSTM layer kernel. 32 blocks: blk 0..15 forward slices, 16..31
// backward slices. Each block owns 16 h-columns -> 64 gate columns. Weights
// (fp32 in HBM) are converted once to bf16 MFMA B-fragments held in registers
// for all 512 steps. A = [x_t | h_{t-1}] staged bf16 in LDS each step.
// Cross-block sync: monotone sum-barrier on a device-scope atomic counter.
// XF32: xin is fp32 (layer 0); else xin is bf16 (layer 1 reads hs0).
// ---------------------------------------------------------------------------
template<int DIN, bool XF32>
__global__ __launch_bounds__(256, 1)
void rec_kernel(const void* __restrict__ xin_v,        // (64, 512, DIN)
                const float* __restrict__ wih_f, const float* __restrict__ whh_f,
                const float* __restrict__ b_f,
                const float* __restrict__ wih_b, const float* __restrict__ whh_b,
                const float* __restrict__ b_b,
                bf16* __restrict__ hsout,               // (64, 512, 512) bf16
                bf16* __restrict__ cat,                 // (64,512,1024) or null
                unsigned int* __restrict__ ctr)
{
    constexpr int KTOT = DIN + HID;          // 384 (l0) / 768 (l1)
    constexpr int NKS  = KTOT / 16;          // MFMA K-steps
    constexpr int ASTR = KTOT*2 + 16;        // LDS A row stride bytes (pad 16B)
    extern __shared__ char smem[];
    float* gatesLds = (float*)(smem + 64*ASTR);     // 64 x 65 fp32
    float* cLds     = gatesLds + 64*65;             // 1024 fp32
    float* biasLds  = cLds + 1024;                  // 64 fp32

    const int tid  = threadIdx.x;
    const int wave = tid >> 6, lane = tid & 63;
    const int blk  = blockIdx.x;
    const int dir  = blk >> 4;               // 0 fwd, 1 bwd
    const int hcol0 = (blk & 15) * 16;

    const float* wih = dir ? wih_b : wih_f;
    const float* whh = dir ? whh_b : whh_f;
    const float* bia = dir ? b_b   : b_f;

    for (int i = tid; i < 1024; i += 256) cLds[i] = 0.0f;
    if (tid < 64) {
        int gate = tid >> 4, j = hcol0 + (tid & 15);
        biasLds[tid] = bia[gate*256 + j];
    }

    const int mi = wave & 1, ni = wave >> 1;
    const int l31 = lane & 31, lh = lane >> 5;

    // preload + convert B fragments (B[k][n]: n = lane&31, k = (lane>>5)*8 + i)
    bf16x8 Breg[NKS];
    {
        int coll = ni*32 + l31;
        int gate = coll >> 4, j = hcol0 + (coll & 15);
        int wrow = gate*256 + j;
        #pragma unroll
        for (int ks = 0; ks < NKS; ks++) {
            int k = ks*16 + lh*8;
            const float* src = (k < DIN) ? (wih + (size_t)wrow*DIN + k)
                                         : (whh + (size_t)wrow*HID + (k - DIN));
            float4 lo = *(const float4*)src;
            float4 hi = *(const float4*)(src + 4);
            bf16x8 b;
            b[0]=(bf16)lo.x; b[1]=(bf16)lo.y; b[2]=(bf16)lo.z; b[3]=(bf16)lo.w;
            b[4]=(bf16)hi.x; b[5]=(bf16)hi.y; b[6]=(bf16)hi.z; b[7]=(bf16)hi.w;
            Breg[ks] = b;
        }
    }
    __syncthreads();

    for (int s = 0; s < TSEQ; s++) {
        const int t = dir ? (TSEQ-1 - s) : s;
        if (s > 0) {
            if (tid == 0) {
                unsigned int target = 32u * (unsigned int)s;
                while (__hip_atomic_load(ctr, __ATOMIC_RELAXED,
                                         __HIP_MEMORY_SCOPE_AGENT) < target) {
                    __builtin_amdgcn_s_sleep(2);
                }
            }
            __syncthreads();
            __threadfence();   // acquire: invalidate stale cached h
        }
        // ---- stage A = [x_t | h_prev] into LDS (bf16) ----
        const int tprev = dir ? t+1 : t-1;
        if (XF32) {
            const float* xf = (const float*)xin_v;
            constexpr int xcpr = DIN/4;                    // 4-float chunks/row
            for (int c = tid; c < 64*xcpr; c += 256) {
                int row = c / xcpr, k0 = (c % xcpr)*4;
                float4 v = *(const float4*)(xf + (size_t)row*TSEQ*DIN
                                            + (size_t)t*DIN + k0);
                bf16 w4[4] = {(bf16)v.x,(bf16)v.y,(bf16)v.z,(bf16)v.w};
                *(uint2*)(smem + row*ASTR + k0*2) = *(uint2*)w4;
            }
        } else {
            const bf16* xb = (const bf16*)xin_v;
            constexpr int xcpr = DIN/8;                    // 8-bf16 chunks/row
            for (int c = tid; c < 64*xcpr; c += 256) {
                int row = c / xcpr, k0 = (c % xcpr)*8;
                uint4 v = *(const uint4*)(xb + (size_t)row*TSEQ*DIN
                                          + (size_t)t*DIN + k0);
                *(uint4*)(smem + row*ASTR + k0*2) = v;
            }
        }
        for (int c = tid; c < 2048; c += 256) {            // h: 64 rows x 32 chunks
            int row = c >> 5, hp = (c & 31)*8;
            uint4 v;
            if (s == 0) v = make_uint4(0,0,0,0);
            else v = *(const uint4*)(hsout + (size_t)row*TSEQ*512
                                     + (size_t)tprev*512 + dir*256 + hp);
            *(uint4*)(smem + row*ASTR + (DIN + hp)*2) = v;
        }
        __syncthreads();

        floatx16 acc;
        #pragma unroll
        for (int r = 0; r < 16; r++) acc[r] = 0.0f;
        const char* abase = smem + (mi*32 + l31)*ASTR + lh*16;
        #pragma unroll
        for (int ks = 0; ks < NKS; ks++) {
            bf16x8 a = *(const bf16x8*)(abase + ks*32);
            acc = __builtin_amdgcn_mfma_f32_32x32x16_bf16(a, Breg[ks], acc, 0, 0, 0);
        }
        // C layout: col = lane&31 (+ni*32), row = (r&3)+8*(r>>2)+4*(lane>>5) (+mi*32)
        #pragma unroll
        for (int r = 0; r < 16; r++) {
            int row = mi*32 + (r&3) + 8*(r>>2) + 4*lh;
            int col = ni*32 + l31;
            gatesLds[row*65 + col] = acc[r];
        }
        __syncthreads();

        // gate math: 4 (n,hcol) cells per thread
        #pragma unroll
        for (int i = 0; i < 4; i++) {
            int cell = tid*4 + i;
            int n = cell >> 4, hc = cell & 15;
            float gI = gatesLds[n*65 + hc]      + biasLds[hc];
            float gF = gatesLds[n*65 + 16+hc]   + biasLds[16+hc];
            float gG = gatesLds[n*65 + 32+hc]   + biasLds[32+hc];
            float gO = gatesLds[n*65 + 48+hc]   + biasLds[48+hc];
            float co = cLds[cell];
            float cn = sigm(gF)*co + sigm(gI)*tanh_fast(gG);
            cLds[cell] = cn;
            float h = sigm(gO)*tanh_fast(cn);
            bf16 hb = (bf16)h;
            size_t off = (size_t)n*TSEQ*512 + (size_t)t*512 + dir*256 + hcol0 + hc;
            hsout[off] = hb;
            if (cat) cat[(size_t)n*TSEQ*1024 + (size_t)t*1024 + 512 + dir*256 + hcol0 + hc] = hb;
        }
        __threadfence();   // release: drain h stores before signaling
        __syncthreads();
        if (tid == 0)
            __hip_atomic_fetch_add(ctr, 1u, __ATOMIC_RELEASE, __HIP_MEMORY_SCOPE_AGENT);
    }
}

// ---------------------------------------------------------------------------
// Shared 64x64 bf16 GEMM main loop. A (rows m, lda) row-major; Bt (rows n,
// ldb) = B^T layout (K contiguous). K % 64 == 0. brows = valid Bt rows.
// ---------------------------------------------------------------------------
__device__ __forceinline__ floatx16 gemm_loop(const bf16* __restrict__ A0,
                                              const bf16* __restrict__ Bt0,
                                              int lda, int ldb, int K, int brows,
                                              char* smem)
{
    const int tid = threadIdx.x;
    const int wave = tid >> 6, lane = tid & 63;
    const int mi = wave & 1, ni = wave >> 1;
    const int l31 = lane & 31, lh = lane >> 5;
    char* At = smem;
    char* Bt = smem + 64*144;
    floatx16 acc;
    #pragma unroll
    for (int r = 0; r < 16; r++) acc[r] = 0.0f;

    for (int kc = 0; kc < K; kc += 64) {
        __syncthreads();
        for (int c = tid; c < 1024; c += 256) {
            int which = c >> 9;
            int idx = c & 511;
            int row = idx >> 3, kch = idx & 7;
            uint4 v;
            if (which == 0) {
                v = *(const uint4*)(A0 + (size_t)row*lda + kc + kch*8);
                *(uint4*)(At + row*144 + kch*16) = v;
            } else {
                if (row < brows) v = *(const uint4*)(Bt0 + (size_t)row*ldb + kc + kch*8);
                else             v = make_uint4(0,0,0,0);
                *(uint4*)(Bt + row*144 + kch*16) = v;
            }
        }
        __syncthreads();
        #pragma unroll
        for (int ks = 0; ks < 4; ks++) {
            bf16x8 a = *(const bf16x8*)(At + (mi*32 + l31)*144 + ks*32 + lh*16);
            bf16x8 b = *(const bf16x8*)(Bt + (ni*32 + l31)*144 + ks*32 + lh*16);
            acc = __builtin_amdgcn_mfma_f32_32x32x16_bf16(a, b, acc, 0, 0, 0);
        }
    }
    return acc;
}

// scores S[n,t,s] = hs1[n,t,:] . hs1[n,s,:]
__global__ __launch_bounds__(256, 2)
void sgemm_scores(const bf16* __restrict__ hs1, float* __restrict__ S)
{
    __shared__ char smem[64*144*2];
    int n = blockIdx.z, tm = blockIdx.x, tn = blockIdx.y;
    const bf16* base = hs1 + (size_t)n*512*512;
    floatx16 acc = gemm_loop(base + (size_t)tm*64*512, base + (size_t)tn*64*512,
                             512, 512, 512, 64, smem);
    int wave = threadIdx.x >> 6, lane = threadIdx.x & 63;
    int mi = wave & 1, ni = wave >> 1;
    #pragma unroll
    for (int r = 0; r < 16; r++) {
        int row = tm*64 + mi*32 + (r&3) + 8*(r>>2) + 4*(lane>>5);
        int col = tn*64 + ni*32 + (lane&31);
        S[(size_t)n*512*512 + (size_t)row*512 + col] = acc[r];
    }
}

__global__ __launch_bounds__(256, 4)
void softmax_rows(const float* __restrict__ S, bf16* __restrict__ P)
{
    int row = blockIdx.x*4 + (threadIdx.x >> 6);
    int lane = threadIdx.x & 63;
    const float* src = S + (size_t)row*512 + lane*8;
    float4 a = *(const float4*)(src);
    float4 b = *(const float4*)(src + 4);
    float v[8] = {a.x,a.y,a.z,a.w,b.x,b.y,b.z,b.w};
    float m = v[0];
    #pragma unroll
    for (int j = 1; j < 8; j++) m = fmaxf(m, v[j]);
    #pragma unroll
    for (int off = 32; off > 0; off >>= 1) m = fmaxf(m, __shfl_xor(m, off));
    float s = 0.0f;
    #pragma unroll
    for (int j = 0; j < 8; j++) { v[j] = __expf(v[j]-m); s += v[j]; }
    #pragma unroll
    for (int off = 32; off > 0; off >>= 1) s += __shfl_xor(s, off);
    float inv = 1.0f/s;
    union { uint4 u; bf16 h[8]; } pk;
    #pragma unroll
    for (int j = 0; j < 8; j++) pk.h[j] = (bf16)(v[j]*inv);
    *(uint4*)(P + (size_t)row*512 + lane*8) = pk.u;
}

// hs1 (n,t,f) -> hs1T (n,f,t)
__global__ __launch_bounds__(256, 2)
void transpose_nt(const bf16* __restrict__ hs1, bf16* __restrict__ hs1T)
{
    __shared__ bf16 tile[64][72];
    int n = blockIdx.z, tX = blockIdx.x, fX = blockIdx.y;
    const bf16* src = hs1 + (size_t)n*512*512;
    for (int c = threadIdx.x; c < 512; c += 256) {
        int row = c >> 3, kch = c & 7;
        *(uint4*)(&tile[row][kch*8]) =
            *(const uint4*)(src + (size_t)(tX*64+row)*512 + fX*64 + kch*8);
    }
    __syncthreads();
    bf16* dst = hs1T + (size_t)n*512*512;
    for (int c = threadIdx.x; c < 512; c += 256) {
        int frow = c >> 3, tch = c & 7;
        bf16 tmp[8];
        #pragma unroll
        for (int j = 0; j < 8; j++) tmp[j] = tile[tch*8+j][frow];
        *(uint4*)(dst + (size_t)(fX*64+frow)*512 + tX*64 + tch*8) = *(uint4*)tmp;
    }
}

// ctx[n,t,f] = sum_s P[n,t,s] * hs1[n,s,f]  -> cat[:, 0:512]
__global__ __launch_bounds__(256, 2)
void ctx_gemm(const bf16* __restrict__ P, const bf16* __restrict__ hs1T,
              bf16* __restrict__ cat)
{
    __shared__ char smem[64*144*2];
    int n = blockIdx.z, tm = blockIdx.x, tn = blockIdx.y;
    const bf16* A0 = P    + (size_t)n*512*512 + (size_t)tm*64*512;
    const bf16* B0 = hs1T + (size_t)n*512*512 + (size_t)tn*64*512;
    floatx16 acc = gemm_loop(A0, B0, 512, 512, 512, 64, smem);
    int wave = threadIdx.x >> 6, lane = threadIdx.x & 63;
    int mi = wave & 1, ni = wave >> 1;
    #pragma unroll
    for (int r = 0; r < 16; r++) {
        int row = tm*64 + mi*32 + (r&3) + 8*(r>>2) + 4*(lane>>5);
        int col = tn*64 + ni*32 + (lane&31);
        cat[((size_t)n*512 + row)*1024 + col] = (bf16)acc[r];
    }
}

__global__ __launch_bounds__(256, 2)
void fc1_gemm(const bf16* __restrict__ cat, const bf16* __restrict__ wb,
              const float* __restrict__ b, float* __restrict__ outp)
{
    __shared__ char smem[64*144*2];
    const bf16* A0 = cat + (size_t)blockIdx.x*64*1024;
    floatx16 acc = gemm_loop(A0, wb, 1024, 1024, 1024, 50, smem);
    int wave = threadIdx.x >> 6, lane = threadIdx.x & 63;
    int mi = wave & 1, ni = wave >> 1;
    #pragma unroll
    for (int r = 0; r < 16; r++) {
        int row = blockIdx.x*64 + mi*32 + (r&3) + 8*(r>>2) + 4*(lane>>5);
        int col = ni*32 + (lane&31);
        if (col < 50) {
            float v = acc[r] + b[col];
            outp[(size_t)row*50 + col] = fmaxf(v, 0.0f);
        }
    }
}

// BN stats per reshaped channel c: elements fc1out[n*25600 + c*512 + q]
__global__ __launch_bounds__(256, 4)
void bn_stats(const float* __restrict__ fc1out, float* __restrict__ stats)
{
    __shared__ float sh[512];
    int c = blockIdx.x;
    float s = 0.0f, ss = 0.0f;
    for (int i = threadIdx.x; i < 32768; i += 256) {
        int n = i >> 9, q = i & 511;
        float x = fc1out[(size_t)n*25600 + c*512 + q];
        s += x; ss += x*x;
    }
    sh[threadIdx.x] = s; sh[256 + threadIdx.x] = ss;
    __syncthreads();
    for (int o = 128; o > 0; o >>= 1) {
        if (threadIdx.x < o) {
            sh[threadIdx.x] += sh[threadIdx.x + o];
            sh[256+threadIdx.x] += sh[256+threadIdx.x + o];
        }
        __syncthreads();
    }
    if (threadIdx.x == 0) {
        float mean = sh[0] / 32768.0f;
        float var  = sh[256] / 32768.0f - mean*mean;
        stats[c]      = mean;
        stats[64 + c] = rsqrtf(var + 1e-5f);
    }
}

__global__ __launch_bounds__(256, 4)
void tail_kernel(const float* __restrict__ fc1out, const float* __restrict__ stats,
                 const float* __restrict__ bng, const float* __restrict__ bnb,
                 const float* __restrict__ fc2w, const float* __restrict__ fc2b,
                 const float* __restrict__ fc3w, const float* __restrict__ fc3b,
                 const float* __restrict__ fc4w, const float* __restrict__ fc4b,
                 float* __restrict__ outp)
{
    __shared__ float W2[1250], W3[250], B2[25], B3[10], W4[20], B4[2];
    __shared__ float G[50], Bb[50], MU[50], IS[50];
    for (int i = threadIdx.x; i < 1250; i += 256) W2[i] = fc2w[i];
    for (int i = threadIdx.x; i < 250;  i += 256) W3[i] = fc3w[i];
    if (threadIdx.x < 25) B2[threadIdx.x] = fc2b[threadIdx.x];
    if (threadIdx.x < 20) W4[threadIdx.x] = fc4w[threadIdx.x];
    if (threadIdx.x < 10) B3[threadIdx.x] = fc3b[threadIdx.x];
    if (threadIdx.x < 2)  B4[threadIdx.x] = fc4b[threadIdx.x];
    if (threadIdx.x < 50) {
        G[threadIdx.x]  = bng[threadIdx.x];
        Bb[threadIdx.x] = bnb[threadIdx.x];
        MU[threadIdx.x] = stats[threadIdx.x];
        IS[threadIdx.x] = stats[64 + threadIdx.x];
    }
    __syncthreads();
    int m = blockIdx.x*256 + threadIdx.x;      // 0..32767 = n*512 + t
    int t = m & 511;
    const float* src = fc1out + (size_t)m*50;
    float x[50];
    #pragma unroll
    for (int c = 0; c < 50; c++) {
        int j = (t*50 + c) >> 9;               // reshaped BN channel
        x[c] = (src[c] - MU[j])*IS[j]*G[j] + Bb[j];
    }
    float y2[25];
    #pragma unroll
    for (int o = 0; o < 25; o++) {
        float a = B2[o];
        for (int c = 0; c < 50; c++) a += x[c]*W2[o*50+c];
        y2[o] = fmaxf(a, 0.0f);
    }
    float y3[10];
    #pragma unroll
    for (int o = 0; o < 10; o++) {
        float a = B3[o];
        for (int c = 0; c < 25; c++) a += y2[c]*W3[o*25+c];
        y3[o] = fmaxf(a, 0.0f);
    }
    #pragma unroll
    for (int o = 0; o < 2; o++) {
        float a = B4[o];
        for (int c = 0; c < 10; c++) a += y3[c]*W4[o*10+c];
        outp[(size_t)m*2 + o] = a;
    }
}

extern "C" void kernel_launch(void* const* d_in, const int* in_sizes, int n_in,
                              void* d_out, int out_size, void* d_ws, size_t ws_size,
                              hipStream_t stream)
{
    const float* x       = (const float*)d_in[0];
    const float* wih_l0f = (const float*)d_in[1];
    const float* whh_l0f = (const float*)d_in[2];
    const float* b_l0f   = (const float*)d_in[3];
    const float* wih_l0b = (const float*)d_in[4];
    const float* whh_l0b = (const float*)d_in[5];
    const float* b_l0b   = (const float*)d_in[6];
    const float* wih_l1f = (const float*)d_in[7];
    const float* whh_l1f = (const float*)d_in[8];
    const float* b_l1f   = (const float*)d_in[9];
    const float* wih_l1b = (const float*)d_in[10];
    const float* whh_l1b = (const float*)d_in[11];
    const float* b_l1b   = (const float*)d_in[12];
    const float* fc1w    = (const float*)d_in[13];
    const float* fc1b    = (const float*)d_in[14];
    const float* bng     = (const float*)d_in[15];
    const float* bnb     = (const float*)d_in[16];
    const float* fc2w    = (const float*)d_in[17];
    const float* fc2b    = (const float*)d_in[18];
    const float* fc3w    = (const float*)d_in[19];
    const float* fc3b    = (const float*)d_in[20];
    const float* fc4w    = (const float*)d_in[21];
    const float* fc4b    = (const float*)d_in[22];

    char* ws = (char*)d_ws;
    unsigned int* ctrs = (unsigned int*)ws;          // [0]: layer0, [16]: layer1
    float* stats = (float*)(ws + 256);               // 128 floats
    bf16* fc1wb  = (bf16*)(ws + 4096);               // 51200 bf16 = 100 KiB
    const size_t SZH = (size_t)32768*512;
    bf16* hs0 = (bf16*)(ws + 4096 + 131072);
    bf16* hs1 = hs0 + SZH;
    bf16* cat = hs1 + SZH;                            // (32768, 1024)
    float* S  = (float*)(cat + SZH*2);                // (32768, 512) fp32
    bf16* P   = (bf16*)((char*)S + SZH*4);            // (32768, 512) bf16
    float* fc1out = (float*)((char*)P + SZH*2);       // (32768, 50) fp32
    bf16* hs1T = (bf16*)S;                            // overlays S (dead after softmax)

    hipMemsetAsync(d_ws, 0, 4096, stream);
    f2b_kernel<<<200, 256, 0, stream>>>(fc1w, fc1wb, 51200);

    constexpr int LDS_L0 = 64*(384*2+16) + 64*65*4 + 1024*4 + 64*4;   // 71168
    constexpr int LDS_L1 = 64*(768*2+16) + 64*65*4 + 1024*4 + 64*4;   // 120320
    hipFuncSetAttribute(reinterpret_cast<const void*>(&rec_kernel<128,true>),
                        hipFuncAttributeMaxDynamicSharedMemorySize, LDS_L0);
    hipFuncSetAttribute(reinterpret_cast<const void*>(&rec_kernel<512,false>),
                        hipFuncAttributeMaxDynamicSharedMemorySize, LDS_L1);

    rec_kernel<128,true><<<32, 256, LDS_L0, stream>>>(x, wih_l0f, whh_l0f, b_l0f,
                                                      wih_l0b, whh_l0b, b_l0b,
                                                      hs0, (bf16*)nullptr, ctrs + 0);
    rec_kernel<512,false><<<32, 256, LDS_L1, stream>>>(hs0, wih_l1f, whh_l1f, b_l1f,
                                                       wih_l1b, whh_l1b, b_l1b,
                                                       hs1, cat, ctrs + 16);
    dim3 g88(8, 8, 64);
    sgemm_scores<<<g88, 256, 0, stream>>>(hs1, S);
    softmax_rows<<<8192, 256, 0, stream>>>(S, P);
    transpose_nt<<<g88, 256, 0, stream>>>(hs1, hs1T);
    ctx_gemm<<<g88, 256, 0, stream>>>(P, hs1T, cat);
    fc1_gemm<<<512, 256, 0, stream>>>(cat, fc1wb, fc1b, fc1out);
    bn_stats<<<50, 256, 0, stream>>>(fc1out, stats);
    tail_kernel<<<128, 256, 0, stream>>>(fc1out, stats, bng, bnb, fc2w, fc2b,
                                         fc3w, fc3b, fc4w, fc4b, (float*)d_out);
    (void)in_sizes; (void)n_in; (void)out_size; (void)ws_size;
}

// Round 3
// 8886.971 us; speedup vs baseline: 1.6485x; 1.6485x over previous
//
#include <hip/hip_runtime.h>
#include <hip/hip_bf16.h>

typedef __bf16 bf16;
typedef __bf16 bf16x8 __attribute__((ext_vector_type(8)));
typedef float floatx16 __attribute__((ext_vector_type(16)));
typedef unsigned long long u64;

#define TSEQ 512
#define HID 256

__device__ __forceinline__ float sigm(float x){ return 1.0f/(1.0f + __expf(-x)); }
__device__ __forceinline__ float tanh_fast(float x){
    float e = __expf(2.0f*x);
    return 1.0f - 2.0f/(e + 1.0f);   // correct limits at +-inf
}

// fp32 -> bf16 converter (for fc1 weight)
__global__ __launch_bounds__(256, 4)
void f2b_kernel(const float* __restrict__ in, bf16* __restrict__ out, int n)
{
    int i = blockIdx.x*256 + threadIdx.x;
    if (i < n) out[i] = (bf16)in[i];
}

// ---------------------------------------------------------------------------
// Persistent BiLSTM layer kernel. 32 blocks: blk 0..15 forward slices, 16..31
// backward slices. Each block owns 16 h-columns -> 64 gate columns. Weights
// (fp32 in HBM) converted once to bf16 MFMA B-fragments held in registers.
// A = [x_t | h_{t-1}] staged bf16 in LDS each step.
// Coherence design: NO fences in the loop. h exchange goes through 8B
// agent-scope relaxed atomics (write-through to LLC, which is cross-XCD
// coherent); x_t loads stay normally cached (L2 never invalidated).
// __syncthreads() drains vmcnt(0) before s_barrier, so write-through h
// stores are globally visible before the RELAXED counter increment.
// ---------------------------------------------------------------------------
template<int DIN, bool XF32>
__global__ __launch_bounds__(256, 1)
void rec_kernel(const void* __restrict__ xin_v,        // (64, 512, DIN)
                const float* __restrict__ wih_f, const float* __restrict__ whh_f,
                const float* __restrict__ b_f,
                const float* __restrict__ wih_b, const float* __restrict__ whh_b,
                const float* __restrict__ b_b,
                bf16* __restrict__ hsout,               // (64, 512, 512) bf16
                bf16* __restrict__ cat,                 // (64,512,1024) or null
                unsigned int* __restrict__ ctrs)        // [dir*32]
{
    constexpr int KTOT = DIN + HID;          // 384 (l0) / 768 (l1)
    constexpr int NKS  = KTOT / 16;          // MFMA K-steps
    constexpr int ASTR = KTOT*2 + 16;        // LDS A row stride bytes (pad 16B)
    extern __shared__ char smem[];
    float* gatesLds = (float*)(smem + 64*ASTR);     // 64 x 65 fp32
    float* cLds     = gatesLds + 64*65;             // 1024 fp32
    float* biasLds  = cLds + 1024;                  // 64 fp32

    const int tid  = threadIdx.x;
    const int wave = tid >> 6, lane = tid & 63;
    const int blk  = blockIdx.x;
    const int dir  = blk >> 4;               // 0 fwd, 1 bwd
    const int hcol0 = (blk & 15) * 16;
    unsigned int* ctr = ctrs + dir*32;       // per-direction counter, own line

    const float* wih = dir ? wih_b : wih_f;
    const float* whh = dir ? whh_b : whh_f;
    const float* bia = dir ? b_b   : b_f;

    for (int i = tid; i < 1024; i += 256) cLds[i] = 0.0f;
    if (tid < 64) {
        int gate = tid >> 4, j = hcol0 + (tid & 15);
        biasLds[tid] = bia[gate*256 + j];
    }

    const int mi = wave & 1, ni = wave >> 1;
    const int l31 = lane & 31, lh = lane >> 5;

    // preload + convert B fragments (B[k][n]: n = lane&31, k = (lane>>5)*8 + i)
    bf16x8 Breg[NKS];
    {
        int coll = ni*32 + l31;
        int gate = coll >> 4, j = hcol0 + (coll & 15);
        int wrow = gate*256 + j;
        #pragma unroll
        for (int ks = 0; ks < NKS; ks++) {
            int k = ks*16 + lh*8;
            const float* src = (k < DIN) ? (wih + (size_t)wrow*DIN + k)
                                         : (whh + (size_t)wrow*HID + (k - DIN));
            float4 lo = *(const float4*)src;
            float4 hi = *(const float4*)(src + 4);
            bf16x8 b;
            b[0]=(bf16)lo.x; b[1]=(bf16)lo.y; b[2]=(bf16)lo.z; b[3]=(bf16)lo.w;
            b[4]=(bf16)hi.x; b[5]=(bf16)hi.y; b[6]=(bf16)hi.z; b[7]=(bf16)hi.w;
            Breg[ks] = b;
        }
    }
    __syncthreads();

    const int grow = tid >> 2;               // gate-math: batch row 0..63
    const int ghc0 = (tid & 3) * 4;          // 4 consecutive h-cols

    for (int s = 0; s < TSEQ; s++) {
        const int t = dir ? (TSEQ-1 - s) : s;
        // ---- stage x_t into LDS (independent of barrier -> prefetch) ----
        if (XF32) {
            const float* xf = (const float*)xin_v;
            constexpr int xcpr = DIN/4;                    // 4-float chunks/row
            for (int c = tid; c < 64*xcpr; c += 256) {
                int row = c / xcpr, k0 = (c % xcpr)*4;
                float4 v = *(const float4*)(xf + (size_t)row*TSEQ*DIN
                                            + (size_t)t*DIN + k0);
                bf16 w4[4] = {(bf16)v.x,(bf16)v.y,(bf16)v.z,(bf16)v.w};
                *(uint2*)(smem + row*ASTR + k0*2) = *(uint2*)w4;
            }
        } else {
            const bf16* xb = (const bf16*)xin_v;
            constexpr int xcpr = DIN/8;                    // 8-bf16 chunks/row
            for (int c = tid; c < 64*xcpr; c += 256) {
                int row = c / xcpr, k0 = (c % xcpr)*8;
                uint4 v = *(const uint4*)(xb + (size_t)row*TSEQ*DIN
                                          + (size_t)t*DIN + k0);
                *(uint4*)(smem + row*ASTR + k0*2) = v;
            }
        }
        // ---- wait for all h(t_prev) slices ----
        if (s > 0 && tid == 0) {
            unsigned int target = 16u * (unsigned int)s;
            while (__hip_atomic_load(ctr, __ATOMIC_RELAXED,
                                     __HIP_MEMORY_SCOPE_AGENT) < target) {
                __builtin_amdgcn_s_sleep(1);
            }
        }
        __syncthreads();
        // ---- stage h_prev via agent-scope (LLC-coherent) loads ----
        const int tprev = dir ? t+1 : t-1;
        for (int c = tid; c < 2048; c += 256) {            // 64 rows x 32 chunks
            int row = c >> 5, hp = (c & 31)*8;
            union { uint4 v; u64 q[2]; } u;
            if (s == 0) { u.q[0] = 0ull; u.q[1] = 0ull; }
            else {
                const u64* p = (const u64*)(hsout + (size_t)row*TSEQ*512
                                            + (size_t)tprev*512 + dir*256 + hp);
                u.q[0] = __hip_atomic_load(p,   __ATOMIC_RELAXED, __HIP_MEMORY_SCOPE_AGENT);
                u.q[1] = __hip_atomic_load(p+1, __ATOMIC_RELAXED, __HIP_MEMORY_SCOPE_AGENT);
            }
            *(uint4*)(smem + row*ASTR + (DIN + hp)*2) = u.v;
        }
        __syncthreads();

        floatx16 acc;
        #pragma unroll
        for (int r = 0; r < 16; r++) acc[r] = 0.0f;
        const char* abase = smem + (mi*32 + l31)*ASTR + lh*16;
        #pragma unroll
        for (int ks = 0; ks < NKS; ks++) {
            bf16x8 a = *(const bf16x8*)(abase + ks*32);
            acc = __builtin_amdgcn_mfma_f32_32x32x16_bf16(a, Breg[ks], acc, 0, 0, 0);
        }
        // C layout: col = lane&31 (+ni*32), row = (r&3)+8*(r>>2)+4*(lane>>5) (+mi*32)
        #pragma unroll
        for (int r = 0; r < 16; r++) {
            int row = mi*32 + (r&3) + 8*(r>>2) + 4*lh;
            int col = ni*32 + l31;
            gatesLds[row*65 + col] = acc[r];
        }
        __syncthreads();

        // gate math: one batch-row, 4 consecutive h-cols per thread -> 8B store
        {
            union { u64 q; bf16 h[4]; } pk;
            #pragma unroll
            for (int i = 0; i < 4; i++) {
                int hc = ghc0 + i;
                float gI = gatesLds[grow*65 + hc]      + biasLds[hc];
                float gF = gatesLds[grow*65 + 16+hc]   + biasLds[16+hc];
                float gG = gatesLds[grow*65 + 32+hc]   + biasLds[32+hc];
                float gO = gatesLds[grow*65 + 48+hc]   + biasLds[48+hc];
                int cell = grow*16 + hc;
                float co = cLds[cell];
                float cn = sigm(gF)*co + sigm(gI)*tanh_fast(gG);
                cLds[cell] = cn;
                pk.h[i] = (bf16)(sigm(gO)*tanh_fast(cn));
            }
            size_t off = (size_t)grow*TSEQ*512 + (size_t)t*512 + dir*256 + hcol0 + ghc0;
            __hip_atomic_store((u64*)(hsout + off), pk.q,
                               __ATOMIC_RELAXED, __HIP_MEMORY_SCOPE_AGENT);
            if (cat)
                *(u64*)(cat + (size_t)grow*TSEQ*1024 + (size_t)t*1024
                        + 512 + dir*256 + hcol0 + ghc0) = pk.q;
        }
        __syncthreads();   // drains vmcnt(0): write-through h stores are visible
        if (tid == 0)
            __hip_atomic_fetch_add(ctr, 1u, __ATOMIC_RELAXED, __HIP_MEMORY_SCOPE_AGENT);
    }
}

// ---------------------------------------------------------------------------
// Shared 64x64 bf16 GEMM main loop. A (rows m, lda) row-major; Bt (rows n,
// ldb) = B^T layout (K contiguous). K % 64 == 0. brows = valid Bt rows.
// ---------------------------------------------------------------------------
__device__ __forceinline__ floatx16 gemm_loop(const bf16* __restrict__ A0,
                                              const bf16* __restrict__ Bt0,
                                              int lda, int ldb, int K, int brows,
                                              char* smem)
{
    const int tid = threadIdx.x;
    const int wave = tid >> 6, lane = tid & 63;
    const int mi = wave & 1, ni = wave >> 1;
    const int l31 = lane & 31, lh = lane >> 5;
    char* At = smem;
    char* Bt = smem + 64*144;
    floatx16 acc;
    #pragma unroll
    for (int r = 0; r < 16; r++) acc[r] = 0.0f;

    for (int kc = 0; kc < K; kc += 64) {
        __syncthreads();
        for (int c = tid; c < 1024; c += 256) {
            int which = c >> 9;
            int idx = c & 511;
            int row = idx >> 3, kch = idx & 7;
            uint4 v;
            if (which == 0) {
                v = *(const uint4*)(A0 + (size_t)row*lda + kc + kch*8);
                *(uint4*)(At + row*144 + kch*16) = v;
            } else {
                if (row < brows) v = *(const uint4*)(Bt0 + (size_t)row*ldb + kc + kch*8);
                else             v = make_uint4(0,0,0,0);
                *(uint4*)(Bt + row*144 + kch*16) = v;
            }
        }
        __syncthreads();
        #pragma unroll
        for (int ks = 0; ks < 4; ks++) {
            bf16x8 a = *(const bf16x8*)(At + (mi*32 + l31)*144 + ks*32 + lh*16);
            bf16x8 b = *(const bf16x8*)(Bt + (ni*32 + l31)*144 + ks*32 + lh*16);
            acc = __builtin_amdgcn_mfma_f32_32x32x16_bf16(a, b, acc, 0, 0, 0);
        }
    }
    return acc;
}

// scores S[n,t,s] = hs1[n,t,:] . hs1[n,s,:]
__global__ __launch_bounds__(256, 2)
void sgemm_scores(const bf16* __restrict__ hs1, float* __restrict__ S)
{
    __shared__ char smem[64*144*2];
    int n = blockIdx.z, tm = blockIdx.x, tn = blockIdx.y;
    const bf16* base = hs1 + (size_t)n*512*512;
    floatx16 acc = gemm_loop(base + (size_t)tm*64*512, base + (size_t)tn*64*512,
                             512, 512, 512, 64, smem);
    int wave = threadIdx.x >> 6, lane = threadIdx.x & 63;
    int mi = wave & 1, ni = wave >> 1;
    #pragma unroll
    for (int r = 0; r < 16; r++) {
        int row = tm*64 + mi*32 + (r&3) + 8*(r>>2) + 4*(lane>>5);
        int col = tn*64 + ni*32 + (lane&31);
        S[(size_t)n*512*512 + (size_t)row*512 + col] = acc[r];
    }
}

__global__ __launch_bounds__(256, 4)
void softmax_rows(const float* __restrict__ S, bf16* __restrict__ P)
{
    int row = blockIdx.x*4 + (threadIdx.x >> 6);
    int lane = threadIdx.x & 63;
    const float* src = S + (size_t)row*512 + lane*8;
    float4 a = *(const float4*)(src);
    float4 b = *(const float4*)(src + 4);
    float v[8] = {a.x,a.y,a.z,a.w,b.x,b.y,b.z,b.w};
    float m = v[0];
    #pragma unroll
    for (int j = 1; j < 8; j++) m = fmaxf(m, v[j]);
    #pragma unroll
    for (int off = 32; off > 0; off >>= 1) m = fmaxf(m, __shfl_xor(m, off));
    float s = 0.0f;
    #pragma unroll
    for (int j = 0; j < 8; j++) { v[j] = __expf(v[j]-m); s += v[j]; }
    #pragma unroll
    for (int off = 32; off > 0; off >>= 1) s += __shfl_xor(s, off);
    float inv = 1.0f/s;
    union { uint4 u; bf16 h[8]; } pk;
    #pragma unroll
    for (int j = 0; j < 8; j++) pk.h[j] = (bf16)(v[j]*inv);
    *(uint4*)(P + (size_t)row*512 + lane*8) = pk.u;
}

// hs1 (n,t,f) -> hs1T (n,f,t)
__global__ __launch_bounds__(256, 2)
void transpose_nt(const bf16* __restrict__ hs1, bf16* __restrict__ hs1T)
{
    __shared__ bf16 tile[64][72];
    int n = blockIdx.z, tX = blockIdx.x, fX = blockIdx.y;
    const bf16* src = hs1 + (size_t)n*512*512;
    for (int c = threadIdx.x; c < 512; c += 256) {
        int row = c >> 3, kch = c & 7;
        *(uint4*)(&tile[row][kch*8]) =
            *(const uint4*)(src + (size_t)(tX*64+row)*512 + fX*64 + kch*8);
    }
    __syncthreads();
    bf16* dst = hs1T + (size_t)n*512*512;
    for (int c = threadIdx.x; c < 512; c += 256) {
        int frow = c >> 3, tch = c & 7;
        bf16 tmp[8];
        #pragma unroll
        for (int j = 0; j < 8; j++) tmp[j] = tile[tch*8+j][frow];
        *(uint4*)(dst + (size_t)(fX*64+frow)*512 + tX*64 + tch*8) = *(uint4*)tmp;
    }
}

// ctx[n,t,f] = sum_s P[n,t,s] * hs1[n,s,f]  -> cat[:, 0:512]
__global__ __launch_bounds__(256, 2)
void ctx_gemm(const bf16* __restrict__ P, const bf16* __restrict__ hs1T,
              bf16* __restrict__ cat)
{
    __shared__ char smem[64*144*2];
    int n = blockIdx.z, tm = blockIdx.x, tn = blockIdx.y;
    const bf16* A0 = P    + (size_t)n*512*512 + (size_t)tm*64*512;
    const bf16* B0 = hs1T + (size_t)n*512*512 + (size_t)tn*64*512;
    floatx16 acc = gemm_loop(A0, B0, 512, 512, 512, 64, smem);
    int wave = threadIdx.x >> 6, lane = threadIdx.x & 63;
    int mi = wave & 1, ni = wave >> 1;
    #pragma unroll
    for (int r = 0; r < 16; r++) {
        int row = tm*64 + mi*32 + (r&3) + 8*(r>>2) + 4*(lane>>5);
        int col = tn*64 + ni*32 + (lane&31);
        cat[((size_t)n*512 + row)*1024 + col] = (bf16)acc[r];
    }
}

__global__ __launch_bounds__(256, 2)
void fc1_gemm(const bf16* __restrict__ cat, const bf16* __restrict__ wb,
              const float* __restrict__ b, float* __restrict__ outp)
{
    __shared__ char smem[64*144*2];
    const bf16* A0 = cat + (size_t)blockIdx.x*64*1024;
    floatx16 acc = gemm_loop(A0, wb, 1024, 1024, 1024, 50, smem);
    int wave = threadIdx.x >> 6, lane = threadIdx.x & 63;
    int mi = wave & 1, ni = wave >> 1;
    #pragma unroll
    for (int r = 0; r < 16; r++) {
        int row = blockIdx.x*64 + mi*32 + (r&3) + 8*(r>>2) + 4*(lane>>5);
        int col = ni*32 + (lane&31);
        if (col < 50) {
            float v = acc[r] + b[col];
            outp[(size_t)row*50 + col] = fmaxf(v, 0.0f);
        }
    }
}

// BN stats per reshaped channel c: elements fc1out[n*25600 + c*512 + q]
__global__ __launch_bounds__(256, 4)
void bn_stats(const float* __restrict__ fc1out, float* __restrict__ stats)
{
    __shared__ float sh[512];
    int c = blockIdx.x;
    float s = 0.0f, ss = 0.0f;
    for (int i = threadIdx.x; i < 32768; i += 256) {
        int n = i >> 9, q = i & 511;
        float x = fc1out[(size_t)n*25600 + c*512 + q];
        s += x; ss += x*x;
    }
    sh[threadIdx.x] = s; sh[256 + threadIdx.x] = ss;
    __syncthreads();
    for (int o = 128; o > 0; o >>= 1) {
        if (threadIdx.x < o) {
            sh[threadIdx.x] += sh[threadIdx.x + o];
            sh[256+threadIdx.x] += sh[256+threadIdx.x + o];
        }
        __syncthreads();
    }
    if (threadIdx.x == 0) {
        float mean = sh[0] / 32768.0f;
        float var  = sh[256] / 32768.0f - mean*mean;
        stats[c]      = mean;
        stats[64 + c] = rsqrtf(var + 1e-5f);
    }
}

__global__ __launch_bounds__(256, 4)
void tail_kernel(const float* __restrict__ fc1out, const float* __restrict__ stats,
                 const float* __restrict__ bng, const float* __restrict__ bnb,
                 const float* __restrict__ fc2w, const float* __restrict__ fc2b,
                 const float* __restrict__ fc3w, const float* __restrict__ fc3b,
                 const float* __restrict__ fc4w, const float* __restrict__ fc4b,
                 float* __restrict__ outp)
{
    __shared__ float W2[1250], W3[250], B2[25], B3[10], W4[20], B4[2];
    __shared__ float G[50], Bb[50], MU[50], IS[50];
    for (int i = threadIdx.x; i < 1250; i += 256) W2[i] = fc2w[i];
    for (int i = threadIdx.x; i < 250;  i += 256) W3[i] = fc3w[i];
    if (threadIdx.x < 25) B2[threadIdx.x] = fc2b[threadIdx.x];
    if (threadIdx.x < 20) W4[threadIdx.x] = fc4w[threadIdx.x];
    if (threadIdx.x < 10) B3[threadIdx.x] = fc3b[threadIdx.x];
    if (threadIdx.x < 2)  B4[threadIdx.x] = fc4b[threadIdx.x];
    if (threadIdx.x < 50) {
        G[threadIdx.x]  = bng[threadIdx.x];
        Bb[threadIdx.x] = bnb[threadIdx.x];
        MU[threadIdx.x] = stats[threadIdx.x];
        IS[threadIdx.x] = stats[64 + threadIdx.x];
    }
    __syncthreads();
    int m = blockIdx.x*256 + threadIdx.x;      // 0..32767 = n*512 + t
    int t = m & 511;
    const float* src = fc1out + (size_t)m*50;
    float x[50];
    #pragma unroll
    for (int c = 0; c < 50; c++) {
        int j = (t*50 + c) >> 9;               // reshaped BN channel
        x[c] = (src[c] - MU[j])*IS[j]*G[j] + Bb[j];
    }
    float y2[25];
    #pragma unroll
    for (int o = 0; o < 25; o++) {
        float a = B2[o];
        for (int c = 0; c < 50; c++) a += x[c]*W2[o*50+c];
        y2[o] = fmaxf(a, 0.0f);
    }
    float y3[10];
    #pragma unroll
    for (int o = 0; o < 10; o++) {
        float a = B3[o];
        for (int c = 0; c < 25; c++) a += y2[c]*W3[o*25+c];
        y3[o] = fmaxf(a, 0.0f);
    }
    #pragma unroll
    for (int o = 0; o < 2; o++) {
        float a = B4[o];
        for (int c = 0; c < 10; c++) a += y3[c]*W4[o*10+c];
        outp[(size_t)m*2 + o] = a;
    }
}

extern "C" void kernel_launch(void* const* d_in, const int* in_sizes, int n_in,
                              void* d_out, int out_size, void* d_ws, size_t ws_size,
                              hipStream_t stream)
{
    const float* x       = (const float*)d_in[0];
    const float* wih_l0f = (const float*)d_in[1];
    const float* whh_l0f = (const float*)d_in[2];
    const float* b_l0f   = (const float*)d_in[3];
    const float* wih_l0b = (const float*)d_in[4];
    const float* whh_l0b = (const float*)d_in[5];
    const float* b_l0b   = (const float*)d_in[6];
    const float* wih_l1f = (const float*)d_in[7];
    const float* whh_l1f = (const float*)d_in[8];
    const float* b_l1f   = (const float*)d_in[9];
    const float* wih_l1b = (const float*)d_in[10];
    const float* whh_l1b = (const float*)d_in[11];
    const float* b_l1b   = (const float*)d_in[12];
    const float* fc1w    = (const float*)d_in[13];
    const float* fc1b    = (const float*)d_in[14];
    const float* bng     = (const float*)d_in[15];
    const float* bnb     = (const float*)d_in[16];
    const float* fc2w    = (const float*)d_in[17];
    const float* fc2b    = (const float*)d_in[18];
    const float* fc3w    = (const float*)d_in[19];
    const float* fc3b    = (const float*)d_in[20];
    const float* fc4w    = (const float*)d_in[21];
    const float* fc4b    = (const float*)d_in[22];

    char* ws = (char*)d_ws;
    unsigned int* ctrs0 = (unsigned int*)ws;          // layer0: [0],[32]
    unsigned int* ctrs1 = (unsigned int*)(ws + 1024); // layer1: [0],[32]
    float* stats = (float*)(ws + 2048);               // 128 floats
    bf16* fc1wb  = (bf16*)(ws + 4096);                // 51200 bf16
    const size_t SZH = (size_t)32768*512;
    bf16* hs0 = (bf16*)(ws + 4096 + 131072);
    bf16* hs1 = hs0 + SZH;
    bf16* cat = hs1 + SZH;                            // (32768, 1024)
    float* S  = (float*)(cat + SZH*2);                // (32768, 512) fp32
    bf16* P   = (bf16*)((char*)S + SZH*4);            // (32768, 512) bf16
    float* fc1out = (float*)((char*)P + SZH*2);       // (32768, 50) fp32
    bf16* hs1T = (bf16*)S;                            // overlays S (dead after softmax)

    hipMemsetAsync(d_ws, 0, 4096, stream);
    f2b_kernel<<<200, 256, 0, stream>>>(fc1w, fc1wb, 51200);

    constexpr int LDS_L0 = 64*(384*2+16) + 64*65*4 + 1024*4 + 64*4;   // 71168
    constexpr int LDS_L1 = 64*(768*2+16) + 64*65*4 + 1024*4 + 64*4;   // 120320
    hipFuncSetAttribute(reinterpret_cast<const void*>(&rec_kernel<128,true>),
                        hipFuncAttributeMaxDynamicSharedMemorySize, LDS_L0);
    hipFuncSetAttribute(reinterpret_cast<const void*>(&rec_kernel<512,false>),
                        hipFuncAttributeMaxDynamicSharedMemorySize, LDS_L1);

    rec_kernel<128,true><<<32, 256, LDS_L0, stream>>>(x, wih_l0f, whh_l0f, b_l0f,
                                                      wih_l0b, whh_l0b, b_l0b,
                                                      hs0, (bf16*)nullptr, ctrs0);
    rec_kernel<512,false><<<32, 256, LDS_L1, stream>>>(hs0, wih_l1f, whh_l1f, b_l1f,
                                                       wih_l1b, whh_l1b, b_l1b,
                                                       hs1, cat, ctrs1);
    dim3 g88(8, 8, 64);
    sgemm_scores<<<g88, 256, 0, stream>>>(hs1, S);
    softmax_rows<<<8192, 256, 0, stream>>>(S, P);
    transpose_nt<<<g88, 256, 0, stream>>>(hs1, hs1T);
    ctx_gemm<<<g88, 256, 0, stream>>>(P, hs1T, cat);
    fc1_gemm<<<512, 256, 0, stream>>>(cat, fc1wb, fc1b, fc1out);
    bn_stats<<<50, 256, 0, stream>>>(fc1out, stats);
    tail_kernel<<<128, 256, 0, stream>>>(fc1out, stats, bng, bnb, fc2w, fc2b,
                                         fc3w, fc3b, fc4w, fc4b, (float*)d_out);
    (void)in_sizes; (void)n_in; (void)out_size; (void)ws_size;
}

// Round 4
// 5207.947 us; speedup vs baseline: 2.8131x; 1.7064x over previous
//
#include <hip/hip_runtime.h>
#include <hip/hip_bf16.h>

typedef __bf16 bf16;
typedef __bf16 bf16x8 __attribute__((ext_vector_type(8)));
typedef float floatx16 __attribute__((ext_vector_type(16)));
typedef unsigned long long u64;

#define TSEQ 512
#define HID 256

__device__ __forceinline__ float sigm(float x){ return 1.0f/(1.0f + __expf(-x)); }
__device__ __forceinline__ float tanh_fast(float x){
    float e = __expf(2.0f*x);
    return 1.0f - 2.0f/(e + 1.0f);   // correct limits at +-inf
}

// fp32 -> bf16 converter (for fc1 weight)
__global__ __launch_bounds__(256, 4)
void f2b_kernel(const float* __restrict__ in, bf16* __restrict__ out, int n)
{
    int i = blockIdx.x*256 + threadIdx.x;
    if (i < n) out[i] = (bf16)in[i];
}

// ---------------------------------------------------------------------------
// Persistent BiLSTM layer kernel. 32 blocks x 512 threads: blk 0..15 forward
// slices, 16..31 backward. Each block owns 16 h-cols -> 64 gate cols.
// K-SPLIT: 8 waves; waves 0-3 (kh=0) do K-steps [0,NKS/2), waves 4-7 (kh=1)
// do [NKS/2,NKS). Each wave holds only Breg[NKS/2] (96 VGPR max) -> NO SPILL
// (round-3 lesson: Breg[48]=192 VGPR spilled to scratch, ~5us/step tax).
// Partial gate tiles go to two LDS regions, summed by gate-math threads.
// Coherence: h exchange via 8B agent-scope relaxed atomics (LLC write-through,
// cross-XCD coherent); no fences in the loop; x_t loads stay L2-cached.
// ---------------------------------------------------------------------------
template<int DIN, bool XF32>
__global__ __launch_bounds__(512, 2)
void rec_kernel(const void* __restrict__ xin_v,        // (64, 512, DIN)
                const float* __restrict__ wih_f, const float* __restrict__ whh_f,
                const float* __restrict__ b_f,
                const float* __restrict__ wih_b, const float* __restrict__ whh_b,
                const float* __restrict__ b_b,
                bf16* __restrict__ hsout,               // (64, 512, 512) bf16
                bf16* __restrict__ cat,                 // (64,512,1024) or null
                unsigned int* __restrict__ ctrs)        // [dir*32]
{
    constexpr int KTOT = DIN + HID;          // 384 (l0) / 768 (l1)
    constexpr int NKS  = KTOT / 16;          // MFMA K-steps total
    constexpr int HN   = NKS / 2;            // K-steps per wave-group
    constexpr int ASTR = KTOT*2 + 16;        // LDS A row stride bytes (pad 16B)
    extern __shared__ char smem[];
    float* gatesLds = (float*)(smem + 64*ASTR);     // 2 x (64 x 65) fp32
    float* cLds     = gatesLds + 2*64*65;           // 1024 fp32
    float* biasLds  = cLds + 1024;                  // 64 fp32

    const int tid  = threadIdx.x;
    const int wave = tid >> 6, lane = tid & 63;
    const int blk  = blockIdx.x;
    const int dir  = blk >> 4;               // 0 fwd, 1 bwd
    const int hcol0 = (blk & 15) * 16;
    unsigned int* ctr = ctrs + dir*32;       // per-direction counter, own line

    const float* wih = dir ? wih_b : wih_f;
    const float* whh = dir ? whh_b : whh_f;
    const float* bia = dir ? b_b   : b_f;

    for (int i = tid; i < 1024; i += 512) cLds[i] = 0.0f;
    if (tid < 64) {
        int gate = tid >> 4, j = hcol0 + (tid & 15);
        biasLds[tid] = bia[gate*256 + j];
    }

    const int kh = wave >> 2;                // K-half
    const int w4 = wave & 3;
    const int mi = w4 & 1, ni = w4 >> 1;
    const int l31 = lane & 31, lh = lane >> 5;

    // preload + convert this wave's half of the B fragments
    // (B[k][n]: n = lane&31, k = (lane>>5)*8 + i), global ks = kh*HN + ks
    bf16x8 Breg[HN];
    {
        int coll = ni*32 + l31;
        int gate = coll >> 4, j = hcol0 + (coll & 15);
        int wrow = gate*256 + j;
        #pragma unroll
        for (int ks = 0; ks < HN; ks++) {
            int k = (kh*HN + ks)*16 + lh*8;
            const float* src = (k < DIN) ? (wih + (size_t)wrow*DIN + k)
                                         : (whh + (size_t)wrow*HID + (k - DIN));
            float4 lo = *(const float4*)src;
            float4 hi = *(const float4*)(src + 4);
            bf16x8 b;
            b[0]=(bf16)lo.x; b[1]=(bf16)lo.y; b[2]=(bf16)lo.z; b[3]=(bf16)lo.w;
            b[4]=(bf16)hi.x; b[5]=(bf16)hi.y; b[6]=(bf16)hi.z; b[7]=(bf16)hi.w;
            Breg[ks] = b;
        }
    }
    __syncthreads();

    const int grow = (tid & 255) >> 2;       // gate-math: batch row 0..63
    const int ghc0 = (tid & 3) * 4;          // 4 consecutive h-cols

    for (int s = 0; s < TSEQ; s++) {
        const int t = dir ? (TSEQ-1 - s) : s;
        // ---- stage x_t into LDS (independent of barrier -> prefetch) ----
        if (XF32) {
            const float* xf = (const float*)xin_v;
            constexpr int xcpr = DIN/4;                    // 4-float chunks/row
            for (int c = tid; c < 64*xcpr; c += 512) {
                int row = c / xcpr, k0 = (c % xcpr)*4;
                float4 v = *(const float4*)(xf + (size_t)row*TSEQ*DIN
                                            + (size_t)t*DIN + k0);
                bf16 w4b[4] = {(bf16)v.x,(bf16)v.y,(bf16)v.z,(bf16)v.w};
                *(uint2*)(smem + row*ASTR + k0*2) = *(uint2*)w4b;
            }
        } else {
            const bf16* xb = (const bf16*)xin_v;
            constexpr int xcpr = DIN/8;                    // 8-bf16 chunks/row
            for (int c = tid; c < 64*xcpr; c += 512) {
                int row = c / xcpr, k0 = (c % xcpr)*8;
                uint4 v = *(const uint4*)(xb + (size_t)row*TSEQ*DIN
                                          + (size_t)t*DIN + k0);
                *(uint4*)(smem + row*ASTR + k0*2) = v;
            }
        }
        // ---- wait for all h(t_prev) slices ----
        if (s > 0 && tid == 0) {
            unsigned int target = 16u * (unsigned int)s;
            while (__hip_atomic_load(ctr, __ATOMIC_RELAXED,
                                     __HIP_MEMORY_SCOPE_AGENT) < target) {
                __builtin_amdgcn_s_sleep(1);
            }
        }
        __syncthreads();
        // ---- stage h_prev via agent-scope (LLC-coherent) loads ----
        const int tprev = dir ? t+1 : t-1;
        for (int c = tid; c < 2048; c += 512) {            // 64 rows x 32 chunks
            int row = c >> 5, hp = (c & 31)*8;
            union { uint4 v; u64 q[2]; } u;
            if (s == 0) { u.q[0] = 0ull; u.q[1] = 0ull; }
            else {
                const u64* p = (const u64*)(hsout + (size_t)row*TSEQ*512
                                            + (size_t)tprev*512 + dir*256 + hp);
                u.q[0] = __hip_atomic_load(p,   __ATOMIC_RELAXED, __HIP_MEMORY_SCOPE_AGENT);
                u.q[1] = __hip_atomic_load(p+1, __ATOMIC_RELAXED, __HIP_MEMORY_SCOPE_AGENT);
            }
            *(uint4*)(smem + row*ASTR + (DIN + hp)*2) = u.v;
        }
        __syncthreads();

        floatx16 acc;
        #pragma unroll
        for (int r = 0; r < 16; r++) acc[r] = 0.0f;
        const char* abase = smem + (mi*32 + l31)*ASTR + kh*(HN*32) + lh*16;
        #pragma unroll
        for (int ks = 0; ks < HN; ks++) {
            bf16x8 a = *(const bf16x8*)(abase + ks*32);
            acc = __builtin_amdgcn_mfma_f32_32x32x16_bf16(a, Breg[ks], acc, 0, 0, 0);
        }
        // C layout: col = lane&31 (+ni*32), row = (r&3)+8*(r>>2)+4*(lane>>5) (+mi*32)
        float* gpart = gatesLds + kh*(64*65);
        #pragma unroll
        for (int r = 0; r < 16; r++) {
            int row = mi*32 + (r&3) + 8*(r>>2) + 4*lh;
            int col = ni*32 + l31;
            gpart[row*65 + col] = acc[r];
        }
        __syncthreads();

        // gate math (threads 0..255): one batch-row, 4 h-cols -> 8B store
        if (tid < 256) {
            const float* g0 = gatesLds + grow*65;
            const float* g1 = g0 + 64*65;
            union { u64 q; bf16 h[4]; } pk;
            #pragma unroll
            for (int i = 0; i < 4; i++) {
                int hc = ghc0 + i;
                float gI = g0[hc]      + g1[hc]      + biasLds[hc];
                float gF = g0[16+hc]   + g1[16+hc]   + biasLds[16+hc];
                float gG = g0[32+hc]   + g1[32+hc]   + biasLds[32+hc];
                float gO = g0[48+hc]   + g1[48+hc]   + biasLds[48+hc];
                int cell = grow*16 + hc;
                float co = cLds[cell];
                float cn = sigm(gF)*co + sigm(gI)*tanh_fast(gG);
                cLds[cell] = cn;
                pk.h[i] = (bf16)(sigm(gO)*tanh_fast(cn));
            }
            size_t off = (size_t)grow*TSEQ*512 + (size_t)t*512 + dir*256 + hcol0 + ghc0;
            __hip_atomic_store((u64*)(hsout + off), pk.q,
                               __ATOMIC_RELAXED, __HIP_MEMORY_SCOPE_AGENT);
            if (cat)
                *(u64*)(cat + (size_t)grow*TSEQ*1024 + (size_t)t*1024
                        + 512 + dir*256 + hcol0 + ghc0) = pk.q;
        }
        __syncthreads();   // drains vmcnt(0): write-through h stores visible
        if (tid == 0)
            __hip_atomic_fetch_add(ctr, 1u, __ATOMIC_RELAXED, __HIP_MEMORY_SCOPE_AGENT);
    }
}

// ---------------------------------------------------------------------------
// Shared 64x64 bf16 GEMM main loop. A (rows m, lda) row-major; Bt (rows n,
// ldb) = B^T layout (K contiguous). K % 64 == 0. brows = valid Bt rows.
// ---------------------------------------------------------------------------
__device__ __forceinline__ floatx16 gemm_loop(const bf16* __restrict__ A0,
                                              const bf16* __restrict__ Bt0,
                                              int lda, int ldb, int K, int brows,
                                              char* smem)
{
    const int tid = threadIdx.x;
    const int wave = tid >> 6, lane = tid & 63;
    const int mi = wave & 1, ni = wave >> 1;
    const int l31 = lane & 31, lh = lane >> 5;
    char* At = smem;
    char* Bt = smem + 64*144;
    floatx16 acc;
    #pragma unroll
    for (int r = 0; r < 16; r++) acc[r] = 0.0f;

    for (int kc = 0; kc < K; kc += 64) {
        __syncthreads();
        for (int c = tid; c < 1024; c += 256) {
            int which = c >> 9;
            int idx = c & 511;
            int row = idx >> 3, kch = idx & 7;
            uint4 v;
            if (which == 0) {
                v = *(const uint4*)(A0 + (size_t)row*lda + kc + kch*8);
                *(uint4*)(At + row*144 + kch*16) = v;
            } else {
                if (row < brows) v = *(const uint4*)(Bt0 + (size_t)row*ldb + kc + kch*8);
                else             v = make_uint4(0,0,0,0);
                *(uint4*)(Bt + row*144 + kch*16) = v;
            }
        }
        __syncthreads();
        #pragma unroll
        for (int ks = 0; ks < 4; ks++) {
            bf16x8 a = *(const bf16x8*)(At + (mi*32 + l31)*144 + ks*32 + lh*16);
            bf16x8 b = *(const bf16x8*)(Bt + (ni*32 + l31)*144 + ks*32 + lh*16);
            acc = __builtin_amdgcn_mfma_f32_32x32x16_bf16(a, b, acc, 0, 0, 0);
        }
    }
    return acc;
}

// scores S[n,t,s] = hs1[n,t,:] . hs1[n,s,:]
__global__ __launch_bounds__(256, 2)
void sgemm_scores(const bf16* __restrict__ hs1, float* __restrict__ S)
{
    __shared__ char smem[64*144*2];
    int n = blockIdx.z, tm = blockIdx.x, tn = blockIdx.y;
    const bf16* base = hs1 + (size_t)n*512*512;
    floatx16 acc = gemm_loop(base + (size_t)tm*64*512, base + (size_t)tn*64*512,
                             512, 512, 512, 64, smem);
    int wave = threadIdx.x >> 6, lane = threadIdx.x & 63;
    int mi = wave & 1, ni = wave >> 1;
    #pragma unroll
    for (int r = 0; r < 16; r++) {
        int row = tm*64 + mi*32 + (r&3) + 8*(r>>2) + 4*(lane>>5);
        int col = tn*64 + ni*32 + (lane&31);
        S[(size_t)n*512*512 + (size_t)row*512 + col] = acc[r];
    }
}

__global__ __launch_bounds__(256, 4)
void softmax_rows(const float* __restrict__ S, bf16* __restrict__ P)
{
    int row = blockIdx.x*4 + (threadIdx.x >> 6);
    int lane = threadIdx.x & 63;
    const float* src = S + (size_t)row*512 + lane*8;
    float4 a = *(const float4*)(src);
    float4 b = *(const float4*)(src + 4);
    float v[8] = {a.x,a.y,a.z,a.w,b.x,b.y,b.z,b.w};
    float m = v[0];
    #pragma unroll
    for (int j = 1; j < 8; j++) m = fmaxf(m, v[j]);
    #pragma unroll
    for (int off = 32; off > 0; off >>= 1) m = fmaxf(m, __shfl_xor(m, off));
    float s = 0.0f;
    #pragma unroll
    for (int j = 0; j < 8; j++) { v[j] = __expf(v[j]-m); s += v[j]; }
    #pragma unroll
    for (int off = 32; off > 0; off >>= 1) s += __shfl_xor(s, off);
    float inv = 1.0f/s;
    union { uint4 u; bf16 h[8]; } pk;
    #pragma unroll
    for (int j = 0; j < 8; j++) pk.h[j] = (bf16)(v[j]*inv);
    *(uint4*)(P + (size_t)row*512 + lane*8) = pk.u;
}

// hs1 (n,t,f) -> hs1T (n,f,t)
__global__ __launch_bounds__(256, 2)
void transpose_nt(const bf16* __restrict__ hs1, bf16* __restrict__ hs1T)
{
    __shared__ bf16 tile[64][72];
    int n = blockIdx.z, tX = blockIdx.x, fX = blockIdx.y;
    const bf16* src = hs1 + (size_t)n*512*512;
    for (int c = threadIdx.x; c < 512; c += 256) {
        int row = c >> 3, kch = c & 7;
        *(uint4*)(&tile[row][kch*8]) =
            *(const uint4*)(src + (size_t)(tX*64+row)*512 + fX*64 + kch*8);
    }
    __syncthreads();
    bf16* dst = hs1T + (size_t)n*512*512;
    for (int c = threadIdx.x; c < 512; c += 256) {
        int frow = c >> 3, tch = c & 7;
        bf16 tmp[8];
        #pragma unroll
        for (int j = 0; j < 8; j++) tmp[j] = tile[tch*8+j][frow];
        *(uint4*)(dst + (size_t)(fX*64+frow)*512 + tX*64 + tch*8) = *(uint4*)tmp;
    }
}

// ctx[n,t,f] = sum_s P[n,t,s] * hs1[n,s,f]  -> cat[:, 0:512]
__global__ __launch_bounds__(256, 2)
void ctx_gemm(const bf16* __restrict__ P, const bf16* __restrict__ hs1T,
              bf16* __restrict__ cat)
{
    __shared__ char smem[64*144*2];
    int n = blockIdx.z, tm = blockIdx.x, tn = blockIdx.y;
    const bf16* A0 = P    + (size_t)n*512*512 + (size_t)tm*64*512;
    const bf16* B0 = hs1T + (size_t)n*512*512 + (size_t)tn*64*512;
    floatx16 acc = gemm_loop(A0, B0, 512, 512, 512, 64, smem);
    int wave = threadIdx.x >> 6, lane = threadIdx.x & 63;
    int mi = wave & 1, ni = wave >> 1;
    #pragma unroll
    for (int r = 0; r < 16; r++) {
        int row = tm*64 + mi*32 + (r&3) + 8*(r>>2) + 4*(lane>>5);
        int col = tn*64 + ni*32 + (lane&31);
        cat[((size_t)n*512 + row)*1024 + col] = (bf16)acc[r];
    }
}

__global__ __launch_bounds__(256, 2)
void fc1_gemm(const bf16* __restrict__ cat, const bf16* __restrict__ wb,
              const float* __restrict__ b, float* __restrict__ outp)
{
    __shared__ char smem[64*144*2];
    const bf16* A0 = cat + (size_t)blockIdx.x*64*1024;
    floatx16 acc = gemm_loop(A0, wb, 1024, 1024, 1024, 50, smem);
    int wave = threadIdx.x >> 6, lane = threadIdx.x & 63;
    int mi = wave & 1, ni = wave >> 1;
    #pragma unroll
    for (int r = 0; r < 16; r++) {
        int row = blockIdx.x*64 + mi*32 + (r&3) + 8*(r>>2) + 4*(lane>>5);
        int col = ni*32 + (lane&31);
        if (col < 50) {
            float v = acc[r] + b[col];
            outp[(size_t)row*50 + col] = fmaxf(v, 0.0f);
        }
    }
}

// BN stats per reshaped channel c: elements fc1out[n*25600 + c*512 + q]
__global__ __launch_bounds__(256, 4)
void bn_stats(const float* __restrict__ fc1out, float* __restrict__ stats)
{
    __shared__ float sh[512];
    int c = blockIdx.x;
    float s = 0.0f, ss = 0.0f;
    for (int i = threadIdx.x; i < 32768; i += 256) {
        int n = i >> 9, q = i & 511;
        float x = fc1out[(size_t)n*25600 + c*512 + q];
        s += x; ss += x*x;
    }
    sh[threadIdx.x] = s; sh[256 + threadIdx.x] = ss;
    __syncthreads();
    for (int o = 128; o > 0; o >>= 1) {
        if (threadIdx.x < o) {
            sh[threadIdx.x] += sh[threadIdx.x + o];
            sh[256+threadIdx.x] += sh[256+threadIdx.x + o];
        }
        __syncthreads();
    }
    if (threadIdx.x == 0) {
        float mean = sh[0] / 32768.0f;
        float var  = sh[256] / 32768.0f - mean*mean;
        stats[c]      = mean;
        stats[64 + c] = rsqrtf(var + 1e-5f);
    }
}

__global__ __launch_bounds__(256, 4)
void tail_kernel(const float* __restrict__ fc1out, const float* __restrict__ stats,
                 const float* __restrict__ bng, const float* __restrict__ bnb,
                 const float* __restrict__ fc2w, const float* __restrict__ fc2b,
                 const float* __restrict__ fc3w, const float* __restrict__ fc3b,
                 const float* __restrict__ fc4w, const float* __restrict__ fc4b,
                 float* __restrict__ outp)
{
    __shared__ float W2[1250], W3[250], B2[25], B3[10], W4[20], B4[2];
    __shared__ float G[50], Bb[50], MU[50], IS[50];
    for (int i = threadIdx.x; i < 1250; i += 256) W2[i] = fc2w[i];
    for (int i = threadIdx.x; i < 250;  i += 256) W3[i] = fc3w[i];
    if (threadIdx.x < 25) B2[threadIdx.x] = fc2b[threadIdx.x];
    if (threadIdx.x < 20) W4[threadIdx.x] = fc4w[threadIdx.x];
    if (threadIdx.x < 10) B3[threadIdx.x] = fc3b[threadIdx.x];
    if (threadIdx.x < 2)  B4[threadIdx.x] = fc4b[threadIdx.x];
    if (threadIdx.x < 50) {
        G[threadIdx.x]  = bng[threadIdx.x];
        Bb[threadIdx.x] = bnb[threadIdx.x];
        MU[threadIdx.x] = stats[threadIdx.x];
        IS[threadIdx.x] = stats[64 + threadIdx.x];
    }
    __syncthreads();
    int m = blockIdx.x*256 + threadIdx.x;      // 0..32767 = n*512 + t
    int t = m & 511;
    const float* src = fc1out + (size_t)m*50;
    float x[50];
    #pragma unroll
    for (int c = 0; c < 50; c++) {
        int j = (t*50 + c) >> 9;               // reshaped BN channel
        x[c] = (src[c] - MU[j])*IS[j]*G[j] + Bb[j];
    }
    float y2[25];
    #pragma unroll
    for (int o = 0; o < 25; o++) {
        float a = B2[o];
        for (int c = 0; c < 50; c++) a += x[c]*W2[o*50+c];
        y2[o] = fmaxf(a, 0.0f);
    }
    float y3[10];
    #pragma unroll
    for (int o = 0; o < 10; o++) {
        float a = B3[o];
        for (int c = 0; c < 25; c++) a += y2[c]*W3[o*25+c];
        y3[o] = fmaxf(a, 0.0f);
    }
    #pragma unroll
    for (int o = 0; o < 2; o++) {
        float a = B4[o];
        for (int c = 0; c < 10; c++) a += y3[c]*W4[o*10+c];
        outp[(size_t)m*2 + o] = a;
    }
}

extern "C" void kernel_launch(void* const* d_in, const int* in_sizes, int n_in,
                              void* d_out, int out_size, void* d_ws, size_t ws_size,
                              hipStream_t stream)
{
    const float* x       = (const float*)d_in[0];
    const float* wih_l0f = (const float*)d_in[1];
    const float* whh_l0f = (const float*)d_in[2];
    const float* b_l0f   = (const float*)d_in[3];
    const float* wih_l0b = (const float*)d_in[4];
    const float* whh_l0b = (const float*)d_in[5];
    const float* b_l0b   = (const float*)d_in[6];
    const float* wih_l1f = (const float*)d_in[7];
    const float* whh_l1f = (const float*)d_in[8];
    const float* b_l1f   = (const float*)d_in[9];
    const float* wih_l1b = (const float*)d_in[10];
    const float* whh_l1b = (const float*)d_in[11];
    const float* b_l1b   = (const float*)d_in[12];
    const float* fc1w    = (const float*)d_in[13];
    const float* fc1b    = (const float*)d_in[14];
    const float* bng     = (const float*)d_in[15];
    const float* bnb     = (const float*)d_in[16];
    const float* fc2w    = (const float*)d_in[17];
    const float* fc2b    = (const float*)d_in[18];
    const float* fc3w    = (const float*)d_in[19];
    const float* fc3b    = (const float*)d_in[20];
    const float* fc4w    = (const float*)d_in[21];
    const float* fc4b    = (const float*)d_in[22];

    char* ws = (char*)d_ws;
    unsigned int* ctrs0 = (unsigned int*)ws;          // layer0: [0],[32]
    unsigned int* ctrs1 = (unsigned int*)(ws + 1024); // layer1: [0],[32]
    float* stats = (float*)(ws + 2048);               // 128 floats
    bf16* fc1wb  = (bf16*)(ws + 4096);                // 51200 bf16
    const size_t SZH = (size_t)32768*512;
    bf16* hs0 = (bf16*)(ws + 4096 + 131072);
    bf16* hs1 = hs0 + SZH;
    bf16* cat = hs1 + SZH;                            // (32768, 1024)
    float* S  = (float*)(cat + SZH*2);                // (32768, 512) fp32
    bf16* P   = (bf16*)((char*)S + SZH*4);            // (32768, 512) bf16
    float* fc1out = (float*)((char*)P + SZH*2);       // (32768, 50) fp32
    bf16* hs1T = (bf16*)S;                            // overlays S (dead after softmax)

    hipMemsetAsync(d_ws, 0, 4096, stream);
    f2b_kernel<<<200, 256, 0, stream>>>(fc1w, fc1wb, 51200);

    constexpr int LDS_L0 = 64*(384*2+16) + 2*64*65*4 + 1024*4 + 64*4;   // 87808
    constexpr int LDS_L1 = 64*(768*2+16) + 2*64*65*4 + 1024*4 + 64*4;   // 136960
    hipFuncSetAttribute(reinterpret_cast<const void*>(&rec_kernel<128,true>),
                        hipFuncAttributeMaxDynamicSharedMemorySize, LDS_L0);
    hipFuncSetAttribute(reinterpret_cast<const void*>(&rec_kernel<512,false>),
                        hipFuncAttributeMaxDynamicSharedMemorySize, LDS_L1);

    rec_kernel<128,true><<<32, 512, LDS_L0, stream>>>(x, wih_l0f, whh_l0f, b_l0f,
                                                      wih_l0b, whh_l0b, b_l0b,
                                                      hs0, (bf16*)nullptr, ctrs0);
    rec_kernel<512,false><<<32, 512, LDS_L1, stream>>>(hs0, wih_l1f, whh_l1f, b_l1f,
                                                       wih_l1b, whh_l1b, b_l1b,
                                                       hs1, cat, ctrs1);
    dim3 g88(8, 8, 64);
    sgemm_scores<<<g88, 256, 0, stream>>>(hs1, S);
    softmax_rows<<<8192, 256, 0, stream>>>(S, P);
    transpose_nt<<<g88, 256, 0, stream>>>(hs1, hs1T);
    ctx_gemm<<<g88, 256, 0, stream>>>(P, hs1T, cat);
    fc1_gemm<<<512, 256, 0, stream>>>(cat, fc1wb, fc1b, fc1out);
    bn_stats<<<50, 256, 0, stream>>>(fc1out, stats);
    tail_kernel<<<128, 256, 0, stream>>>(fc1out, stats, bng, bnb, fc2w, fc2b,
                                         fc3w, fc3b, fc4w, fc4b, (float*)d_out);
    (void)in_sizes; (void)n_in; (void)out_size; (void)ws_size;
}

// Round 5
// 4161.145 us; speedup vs baseline: 3.5208x; 1.2516x over previous
//
#include <hip/hip_runtime.h>
#include <hip/hip_bf16.h>

typedef __bf16 bf16;
typedef __bf16 bf16x8 __attribute__((ext_vector_type(8)));
typedef float floatx16 __attribute__((ext_vector_type(16)));
typedef unsigned int u32x4 __attribute__((ext_vector_type(4)));
typedef unsigned long long u64;

#define TSEQ 512
#define HID 256

__device__ __forceinline__ float sigm(float x){ return 1.0f/(1.0f + __expf(-x)); }
__device__ __forceinline__ float tanh_fast(float x){
    float e = __expf(2.0f*x);
    return 1.0f - 2.0f/(e + 1.0f);   // correct limits at +-inf
}

// fp32 -> bf16 converter (for fc1 weight)
__global__ __launch_bounds__(256, 4)
void f2b_kernel(const float* __restrict__ in, bf16* __restrict__ out, int n)
{
    int i = blockIdx.x*256 + threadIdx.x;
    if (i < n) out[i] = (bf16)in[i];
}

// ---------------------------------------------------------------------------
// Persistent BiLSTM layer kernel. 32 blocks x 512 threads: blk 0..15 forward
// slices, 16..31 backward. Each block owns 16 h-cols -> 64 gate cols.
// K-split across 2 wave-groups (no Breg spill: round-3 lesson).
// Step-chain design (round-5): per-block FLAGS (no RMW counter contention),
// all-wave polling, 16B sc0/sc1 LLC-bypass h loads (one vmcnt wait),
// x_t staged at loop TAIL (off the critical path), no cat store.
// ---------------------------------------------------------------------------
template<int DIN, bool XF32>
__global__ __launch_bounds__(512, 2)
void rec_kernel(const void* __restrict__ xin_v,        // (64, 512, DIN)
                const float* __restrict__ wih_f, const float* __restrict__ whh_f,
                const float* __restrict__ b_f,
                const float* __restrict__ wih_b, const float* __restrict__ whh_b,
                const float* __restrict__ b_b,
                bf16* __restrict__ hsout,               // (64, 512, 512) bf16
                unsigned int* __restrict__ flags_base)  // dir*64 u32
{
    constexpr int KTOT = DIN + HID;          // 384 (l0) / 768 (l1)
    constexpr int NKS  = KTOT / 16;          // MFMA K-steps total
    constexpr int HN   = NKS / 2;            // K-steps per wave-group
    constexpr int ASTR = KTOT*2 + 16;        // LDS A row stride bytes (pad 16B)
    extern __shared__ char smem[];
    float* gatesLds = (float*)(smem + 64*ASTR);     // 2 x (64 x 65) fp32
    float* cLds     = gatesLds + 2*64*65;           // 1024 fp32
    float* biasLds  = cLds + 1024;                  // 64 fp32

    const int tid  = threadIdx.x;
    const int wave = tid >> 6, lane = tid & 63;
    const int blk  = blockIdx.x;
    const int dir  = blk >> 4;               // 0 fwd, 1 bwd
    const int hcol0 = (blk & 15) * 16;
    unsigned int* flg = flags_base + dir*64; // 16 flags, own cache line per dir

    const float* wih = dir ? wih_b : wih_f;
    const float* whh = dir ? whh_b : whh_f;
    const float* bia = dir ? b_b   : b_f;

    for (int i = tid; i < 1024; i += 512) cLds[i] = 0.0f;
    if (tid < 64) {
        int gate = tid >> 4, j = hcol0 + (tid & 15);
        biasLds[tid] = bia[gate*256 + j];
    }

    const int kh = wave >> 2;                // K-half
    const int w4 = wave & 3;
    const int mi = w4 & 1, ni = w4 >> 1;
    const int l31 = lane & 31, lh = lane >> 5;

    // preload + convert this wave's half of the B fragments
    bf16x8 Breg[HN];
    {
        int coll = ni*32 + l31;
        int gate = coll >> 4, j = hcol0 + (coll & 15);
        int wrow = gate*256 + j;
        #pragma unroll
        for (int ks = 0; ks < HN; ks++) {
            int k = (kh*HN + ks)*16 + lh*8;
            const float* src = (k < DIN) ? (wih + (size_t)wrow*DIN + k)
                                         : (whh + (size_t)wrow*HID + (k - DIN));
            float4 lo = *(const float4*)src;
            float4 hi = *(const float4*)(src + 4);
            bf16x8 b;
            b[0]=(bf16)lo.x; b[1]=(bf16)lo.y; b[2]=(bf16)lo.z; b[3]=(bf16)lo.w;
            b[4]=(bf16)hi.x; b[5]=(bf16)hi.y; b[6]=(bf16)hi.z; b[7]=(bf16)hi.w;
            Breg[ks] = b;
        }
    }
    __syncthreads();

    const int grow = (tid & 255) >> 2;       // gate-math: batch row 0..63
    const int ghc0 = (tid & 3) * 4;          // 4 consecutive h-cols

    auto stage_x = [&](int t) {
        if constexpr (XF32) {
            const float* xf = (const float*)xin_v;
            constexpr int xcpr = DIN/4;                    // 4-float chunks/row
            for (int c = tid; c < 64*xcpr; c += 512) {
                int row = c / xcpr, k0 = (c % xcpr)*4;
                float4 v = *(const float4*)(xf + (size_t)row*TSEQ*DIN
                                            + (size_t)t*DIN + k0);
                bf16 w4b[4] = {(bf16)v.x,(bf16)v.y,(bf16)v.z,(bf16)v.w};
                *(uint2*)(smem + row*ASTR + k0*2) = *(uint2*)w4b;
            }
        } else {
            const bf16* xb = (const bf16*)xin_v;
            constexpr int xcpr = DIN/8;                    // 8-bf16 chunks/row
            for (int c = tid; c < 64*xcpr; c += 512) {
                int row = c / xcpr, k0 = (c % xcpr)*8;
                uint4 v = *(const uint4*)(xb + (size_t)row*TSEQ*DIN
                                          + (size_t)t*DIN + k0);
                *(uint4*)(smem + row*ASTR + k0*2) = v;
            }
        }
    };

    stage_x(dir ? TSEQ-1 : 0);

    const int hrow0 = tid >> 5;              // h-stage: rows hrow0 + 16*j
    const int hcolp = (tid & 31) * 8;        // 8 bf16 cols = 16B

    for (int s = 0; s < TSEQ; s++) {
        const int t = dir ? (TSEQ-1 - s) : s;
        // ---- all-wave poll for h(t_prev) readiness ----
        if (s > 0) {
            unsigned int tgt = (unsigned int)s;
            for (;;) {
                unsigned int f = __hip_atomic_load(flg + (lane & 15),
                                                   __ATOMIC_RELAXED,
                                                   __HIP_MEMORY_SCOPE_AGENT);
                if (__all(f >= tgt)) break;
                __builtin_amdgcn_s_sleep(1);
            }
        }
        // ---- stage h_prev: 4 x 16B LLC-bypass loads, one wait ----
        if (s == 0) {
            u32x4 z = {0u,0u,0u,0u};
            #pragma unroll
            for (int j = 0; j < 4; j++)
                *(u32x4*)(smem + (hrow0 + 16*j)*ASTR + (DIN + hcolp)*2) = z;
        } else {
            const int tprev = dir ? t+1 : t-1;
            const bf16* p0 = hsout + (size_t)hrow0*TSEQ*512
                             + (size_t)tprev*512 + dir*256 + hcolp;
            const bf16* p1 = p0 + (size_t)16*TSEQ*512;
            const bf16* p2 = p0 + (size_t)32*TSEQ*512;
            const bf16* p3 = p0 + (size_t)48*TSEQ*512;
            u32x4 r0, r1, r2, r3;
            asm volatile(
                "global_load_dwordx4 %0, %4, off sc0 sc1\n\t"
                "global_load_dwordx4 %1, %5, off sc0 sc1\n\t"
                "global_load_dwordx4 %2, %6, off sc0 sc1\n\t"
                "global_load_dwordx4 %3, %7, off sc0 sc1\n\t"
                "s_waitcnt vmcnt(0)"
                : "=&v"(r0), "=&v"(r1), "=&v"(r2), "=&v"(r3)
                : "v"((const void*)p0), "v"((const void*)p1),
                  "v"((const void*)p2), "v"((const void*)p3)
                : "memory");
            *(u32x4*)(smem + (hrow0     )*ASTR + (DIN + hcolp)*2) = r0;
            *(u32x4*)(smem + (hrow0 + 16)*ASTR + (DIN + hcolp)*2) = r1;
            *(u32x4*)(smem + (hrow0 + 32)*ASTR + (DIN + hcolp)*2) = r2;
            *(u32x4*)(smem + (hrow0 + 48)*ASTR + (DIN + hcolp)*2) = r3;
        }
        __syncthreads();

        floatx16 acc;
        #pragma unroll
        for (int r = 0; r < 16; r++) acc[r] = 0.0f;
        const char* abase = smem + (mi*32 + l31)*ASTR + kh*(HN*32) + lh*16;
        #pragma unroll
        for (int ks = 0; ks < HN; ks++) {
            bf16x8 a = *(const bf16x8*)(abase + ks*32);
            acc = __builtin_amdgcn_mfma_f32_32x32x16_bf16(a, Breg[ks], acc, 0, 0, 0);
        }
        // C layout: col = lane&31 (+ni*32), row = (r&3)+8*(r>>2)+4*(lane>>5)
        float* gpart = gatesLds + kh*(64*65);
        #pragma unroll
        for (int r = 0; r < 16; r++) {
            int row = mi*32 + (r&3) + 8*(r>>2) + 4*lh;
            int col = ni*32 + l31;
            gpart[row*65 + col] = acc[r];
        }
        __syncthreads();

        // gate math (threads 0..255): one batch-row, 4 h-cols -> 8B store
        if (tid < 256) {
            const float* g0 = gatesLds + grow*65;
            const float* g1 = g0 + 64*65;
            union { u64 q; bf16 h[4]; } pk;
            #pragma unroll
            for (int i = 0; i < 4; i++) {
                int hc = ghc0 + i;
                float gI = g0[hc]      + g1[hc]      + biasLds[hc];
                float gF = g0[16+hc]   + g1[16+hc]   + biasLds[16+hc];
                float gG = g0[32+hc]   + g1[32+hc]   + biasLds[32+hc];
                float gO = g0[48+hc]   + g1[48+hc]   + biasLds[48+hc];
                int cell = grow*16 + hc;
                float co = cLds[cell];
                float cn = sigm(gF)*co + sigm(gI)*tanh_fast(gG);
                cLds[cell] = cn;
                pk.h[i] = (bf16)(sigm(gO)*tanh_fast(cn));
            }
            size_t off = (size_t)grow*TSEQ*512 + (size_t)t*512 + dir*256 + hcol0 + ghc0;
            __hip_atomic_store((u64*)(hsout + off), pk.q,
                               __ATOMIC_RELAXED, __HIP_MEMORY_SCOPE_AGENT);
        }
        __syncthreads();   // per-wave vmcnt(0) drain: h stores visible at LLC
        if (tid == 0)
            __hip_atomic_store(flg + (blk & 15), (unsigned int)(s+1),
                               __ATOMIC_RELAXED, __HIP_MEMORY_SCOPE_AGENT);
        if (s+1 < TSEQ) stage_x(dir ? t-1 : t+1);   // off critical path
    }
}

// ---------------------------------------------------------------------------
// Shared 64x64 bf16 GEMM main loop. A (rows m, lda) row-major; Bt (rows n,
// ldb) = B^T layout (K contiguous). K % 64 == 0. brows = valid Bt rows.
// ---------------------------------------------------------------------------
__device__ __forceinline__ floatx16 gemm_loop(const bf16* __restrict__ A0,
                                              const bf16* __restrict__ Bt0,
                                              int lda, int ldb, int K, int brows,
                                              char* smem)
{
    const int tid = threadIdx.x;
    const int wave = tid >> 6, lane = tid & 63;
    const int mi = wave & 1, ni = wave >> 1;
    const int l31 = lane & 31, lh = lane >> 5;
    char* At = smem;
    char* Bt = smem + 64*144;
    floatx16 acc;
    #pragma unroll
    for (int r = 0; r < 16; r++) acc[r] = 0.0f;

    for (int kc = 0; kc < K; kc += 64) {
        __syncthreads();
        for (int c = tid; c < 1024; c += 256) {
            int which = c >> 9;
            int idx = c & 511;
            int row = idx >> 3, kch = idx & 7;
            uint4 v;
            if (which == 0) {
                v = *(const uint4*)(A0 + (size_t)row*lda + kc + kch*8);
                *(uint4*)(At + row*144 + kch*16) = v;
            } else {
                if (row < brows) v = *(const uint4*)(Bt0 + (size_t)row*ldb + kc + kch*8);
                else             v = make_uint4(0,0,0,0);
                *(uint4*)(Bt + row*144 + kch*16) = v;
            }
        }
        __syncthreads();
        #pragma unroll
        for (int ks = 0; ks < 4; ks++) {
            bf16x8 a = *(const bf16x8*)(At + (mi*32 + l31)*144 + ks*32 + lh*16);
            bf16x8 b = *(const bf16x8*)(Bt + (ni*32 + l31)*144 + ks*32 + lh*16);
            acc = __builtin_amdgcn_mfma_f32_32x32x16_bf16(a, b, acc, 0, 0, 0);
        }
    }
    return acc;
}

// scores S[n,t,s] = hs1[n,t,:] . hs1[n,s,:]
__global__ __launch_bounds__(256, 2)
void sgemm_scores(const bf16* __restrict__ hs1, float* __restrict__ S)
{
    __shared__ char smem[64*144*2];
    int n = blockIdx.z, tm = blockIdx.x, tn = blockIdx.y;
    const bf16* base = hs1 + (size_t)n*512*512;
    floatx16 acc = gemm_loop(base + (size_t)tm*64*512, base + (size_t)tn*64*512,
                             512, 512, 512, 64, smem);
    int wave = threadIdx.x >> 6, lane = threadIdx.x & 63;
    int mi = wave & 1, ni = wave >> 1;
    #pragma unroll
    for (int r = 0; r < 16; r++) {
        int row = tm*64 + mi*32 + (r&3) + 8*(r>>2) + 4*(lane>>5);
        int col = tn*64 + ni*32 + (lane&31);
        S[(size_t)n*512*512 + (size_t)row*512 + col] = acc[r];
    }
}

__global__ __launch_bounds__(256, 4)
void softmax_rows(const float* __restrict__ S, bf16* __restrict__ P)
{
    int row = blockIdx.x*4 + (threadIdx.x >> 6);
    int lane = threadIdx.x & 63;
    const float* src = S + (size_t)row*512 + lane*8;
    float4 a = *(const float4*)(src);
    float4 b = *(const float4*)(src + 4);
    float v[8] = {a.x,a.y,a.z,a.w,b.x,b.y,b.z,b.w};
    float m = v[0];
    #pragma unroll
    for (int j = 1; j < 8; j++) m = fmaxf(m, v[j]);
    #pragma unroll
    for (int off = 32; off > 0; off >>= 1) m = fmaxf(m, __shfl_xor(m, off));
    float s = 0.0f;
    #pragma unroll
    for (int j = 0; j < 8; j++) { v[j] = __expf(v[j]-m); s += v[j]; }
    #pragma unroll
    for (int off = 32; off > 0; off >>= 1) s += __shfl_xor(s, off);
    float inv = 1.0f/s;
    union { uint4 u; bf16 h[8]; } pk;
    #pragma unroll
    for (int j = 0; j < 8; j++) pk.h[j] = (bf16)(v[j]*inv);
    *(uint4*)(P + (size_t)row*512 + lane*8) = pk.u;
}

// hs1 (n,t,f) -> hs1T (n,f,t)
__global__ __launch_bounds__(256, 2)
void transpose_nt(const bf16* __restrict__ hs1, bf16* __restrict__ hs1T)
{
    __shared__ bf16 tile[64][72];
    int n = blockIdx.z, tX = blockIdx.x, fX = blockIdx.y;
    const bf16* src = hs1 + (size_t)n*512*512;
    for (int c = threadIdx.x; c < 512; c += 256) {
        int row = c >> 3, kch = c & 7;
        *(uint4*)(&tile[row][kch*8]) =
            *(const uint4*)(src + (size_t)(tX*64+row)*512 + fX*64 + kch*8);
    }
    __syncthreads();
    bf16* dst = hs1T + (size_t)n*512*512;
    for (int c = threadIdx.x; c < 512; c += 256) {
        int frow = c >> 3, tch = c & 7;
        bf16 tmp[8];
        #pragma unroll
        for (int j = 0; j < 8; j++) tmp[j] = tile[tch*8+j][frow];
        *(uint4*)(dst + (size_t)(fX*64+frow)*512 + tX*64 + tch*8) = *(uint4*)tmp;
    }
}

// ctx[n,t,f] = sum_s P[n,t,s] * hs1[n,s,f]
__global__ __launch_bounds__(256, 2)
void ctx_gemm(const bf16* __restrict__ P, const bf16* __restrict__ hs1T,
              bf16* __restrict__ ctx)
{
    __shared__ char smem[64*144*2];
    int n = blockIdx.z, tm = blockIdx.x, tn = blockIdx.y;
    const bf16* A0 = P    + (size_t)n*512*512 + (size_t)tm*64*512;
    const bf16* B0 = hs1T + (size_t)n*512*512 + (size_t)tn*64*512;
    floatx16 acc = gemm_loop(A0, B0, 512, 512, 512, 64, smem);
    int wave = threadIdx.x >> 6, lane = threadIdx.x & 63;
    int mi = wave & 1, ni = wave >> 1;
    #pragma unroll
    for (int r = 0; r < 16; r++) {
        int row = tm*64 + mi*32 + (r&3) + 8*(r>>2) + 4*(lane>>5);
        int col = tn*64 + ni*32 + (lane&31);
        ctx[((size_t)n*512 + row)*512 + col] = (bf16)acc[r];
    }
}

// fc1: A = [ctx | hs1] (32768 x 1024, two 512-wide sources), B = fc1w (50x1024)
__global__ __launch_bounds__(256, 2)
void fc1_gemm(const bf16* __restrict__ ctx, const bf16* __restrict__ hs1,
              const bf16* __restrict__ wb, const float* __restrict__ b,
              float* __restrict__ outp)
{
    __shared__ char smem[64*144*2];
    const int tid = threadIdx.x;
    const int wave = tid >> 6, lane = tid & 63;
    const int mi = wave & 1, ni = wave >> 1;
    const int l31 = lane & 31, lh = lane >> 5;
    char* At = smem;
    char* Bt = smem + 64*144;
    const int m0 = blockIdx.x*64;
    floatx16 acc;
    #pragma unroll
    for (int r = 0; r < 16; r++) acc[r] = 0.0f;

    for (int kc = 0; kc < 1024; kc += 64) {
        const bf16* Asrc = (kc < 512) ? ctx : hs1;
        const int koff = kc & 511;
        __syncthreads();
        for (int c = tid; c < 1024; c += 256) {
            int which = c >> 9, idx = c & 511;
            int row = idx >> 3, kch = idx & 7;
            uint4 v;
            if (which == 0) {
                v = *(const uint4*)(Asrc + (size_t)(m0+row)*512 + koff + kch*8);
                *(uint4*)(At + row*144 + kch*16) = v;
            } else {
                if (row < 50) v = *(const uint4*)(wb + (size_t)row*1024 + kc + kch*8);
                else          v = make_uint4(0,0,0,0);
                *(uint4*)(Bt + row*144 + kch*16) = v;
            }
        }
        __syncthreads();
        #pragma unroll
        for (int ks = 0; ks < 4; ks++) {
            bf16x8 a = *(const bf16x8*)(At + (mi*32 + l31)*144 + ks*32 + lh*16);
            bf16x8 bb = *(const bf16x8*)(Bt + (ni*32 + l31)*144 + ks*32 + lh*16);
            acc = __builtin_amdgcn_mfma_f32_32x32x16_bf16(a, bb, acc, 0, 0, 0);
        }
    }
    #pragma unroll
    for (int r = 0; r < 16; r++) {
        int row = m0 + mi*32 + (r&3) + 8*(r>>2) + 4*lh;
        int col = ni*32 + l31;
        if (col < 50) {
            float v = acc[r] + b[col];
            outp[(size_t)row*50 + col] = fmaxf(v, 0.0f);
        }
    }
}

// BN stats per reshaped channel c: elements fc1out[n*25600 + c*512 + q]
__global__ __launch_bounds__(256, 4)
void bn_stats(const float* __restrict__ fc1out, float* __restrict__ stats)
{
    __shared__ float sh[512];
    int c = blockIdx.x;
    float s = 0.0f, ss = 0.0f;
    for (int i = threadIdx.x; i < 32768; i += 256) {
        int n = i >> 9, q = i & 511;
        float x = fc1out[(size_t)n*25600 + c*512 + q];
        s += x; ss += x*x;
    }
    sh[threadIdx.x] = s; sh[256 + threadIdx.x] = ss;
    __syncthreads();
    for (int o = 128; o > 0; o >>= 1) {
        if (threadIdx.x < o) {
            sh[threadIdx.x] += sh[threadIdx.x + o];
            sh[256+threadIdx.x] += sh[256+threadIdx.x + o];
        }
        __syncthreads();
    }
    if (threadIdx.x == 0) {
        float mean = sh[0] / 32768.0f;
        float var  = sh[256] / 32768.0f - mean*mean;
        stats[c]      = mean;
        stats[64 + c] = rsqrtf(var + 1e-5f);
    }
}

__global__ __launch_bounds__(256, 4)
void tail_kernel(const float* __restrict__ fc1out, const float* __restrict__ stats,
                 const float* __restrict__ bng, const float* __restrict__ bnb,
                 const float* __restrict__ fc2w, const float* __restrict__ fc2b,
                 const float* __restrict__ fc3w, const float* __restrict__ fc3b,
                 const float* __restrict__ fc4w, const float* __restrict__ fc4b,
                 float* __restrict__ outp)
{
    __shared__ float W2[1250], W3[250], B2[25], B3[10], W4[20], B4[2];
    __shared__ float G[50], Bb[50], MU[50], IS[50];
    for (int i = threadIdx.x; i < 1250; i += 256) W2[i] = fc2w[i];
    for (int i = threadIdx.x; i < 250;  i += 256) W3[i] = fc3w[i];
    if (threadIdx.x < 25) B2[threadIdx.x] = fc2b[threadIdx.x];
    if (threadIdx.x < 20) W4[threadIdx.x] = fc4w[threadIdx.x];
    if (threadIdx.x < 10) B3[threadIdx.x] = fc3b[threadIdx.x];
    if (threadIdx.x < 2)  B4[threadIdx.x] = fc4b[threadIdx.x];
    if (threadIdx.x < 50) {
        G[threadIdx.x]  = bng[threadIdx.x];
        Bb[threadIdx.x] = bnb[threadIdx.x];
        MU[threadIdx.x] = stats[threadIdx.x];
        IS[threadIdx.x] = stats[64 + threadIdx.x];
    }
    __syncthreads();
    int m = blockIdx.x*256 + threadIdx.x;      // 0..32767 = n*512 + t
    int t = m & 511;
    const float* src = fc1out + (size_t)m*50;
    float x[50];
    #pragma unroll
    for (int c = 0; c < 50; c++) {
        int j = (t*50 + c) >> 9;               // reshaped BN channel
        x[c] = (src[c] - MU[j])*IS[j]*G[j] + Bb[j];
    }
    float y2[25];
    #pragma unroll
    for (int o = 0; o < 25; o++) {
        float a = B2[o];
        for (int c = 0; c < 50; c++) a += x[c]*W2[o*50+c];
        y2[o] = fmaxf(a, 0.0f);
    }
    float y3[10];
    #pragma unroll
    for (int o = 0; o < 10; o++) {
        float a = B3[o];
        for (int c = 0; c < 25; c++) a += y2[c]*W3[o*25+c];
        y3[o] = fmaxf(a, 0.0f);
    }
    #pragma unroll
    for (int o = 0; o < 2; o++) {
        float a = B4[o];
        for (int c = 0; c < 10; c++) a += y3[c]*W4[o*10+c];
        outp[(size_t)m*2 + o] = a;
    }
}

extern "C" void kernel_launch(void* const* d_in, const int* in_sizes, int n_in,
                              void* d_out, int out_size, void* d_ws, size_t ws_size,
                              hipStream_t stream)
{
    const float* x       = (const float*)d_in[0];
    const float* wih_l0f = (const float*)d_in[1];
    const float* whh_l0f = (const float*)d_in[2];
    const float* b_l0f   = (const float*)d_in[3];
    const float* wih_l0b = (const float*)d_in[4];
    const float* whh_l0b = (const float*)d_in[5];
    const float* b_l0b   = (const float*)d_in[6];
    const float* wih_l1f = (const float*)d_in[7];
    const float* whh_l1f = (const float*)d_in[8];
    const float* b_l1f   = (const float*)d_in[9];
    const float* wih_l1b = (const float*)d_in[10];
    const float* whh_l1b = (const float*)d_in[11];
    const float* b_l1b   = (const float*)d_in[12];
    const float* fc1w    = (const float*)d_in[13];
    const float* fc1b    = (const float*)d_in[14];
    const float* bng     = (const float*)d_in[15];
    const float* bnb     = (const float*)d_in[16];
    const float* fc2w    = (const float*)d_in[17];
    const float* fc2b    = (const float*)d_in[18];
    const float* fc3w    = (const float*)d_in[19];
    const float* fc3b    = (const float*)d_in[20];
    const float* fc4w    = (const float*)d_in[21];
    const float* fc4b    = (const float*)d_in[22];

    char* ws = (char*)d_ws;
    unsigned int* flags0 = (unsigned int*)ws;          // layer0: dir0 @0, dir1 @+256B
    unsigned int* flags1 = (unsigned int*)(ws + 1024); // layer1
    float* stats = (float*)(ws + 2048);                // 128 floats
    bf16* fc1wb  = (bf16*)(ws + 4096);                 // 51200 bf16
    const size_t SZH = (size_t)32768*512;
    bf16* hs0 = (bf16*)(ws + 4096 + 131072);
    bf16* hs1 = hs0 + SZH;
    bf16* ctx = hs1 + SZH;                             // (32768, 512) bf16
    float* S  = (float*)(ctx + SZH);                   // (32768, 512) fp32
    bf16* P   = (bf16*)((char*)S + SZH*4);             // (32768, 512) bf16
    float* fc1out = (float*)((char*)P + SZH*2);        // (32768, 50) fp32
    bf16* hs1T = (bf16*)S;                             // overlays S (dead after softmax)

    hipMemsetAsync(d_ws, 0, 4096, stream);
    f2b_kernel<<<200, 256, 0, stream>>>(fc1w, fc1wb, 51200);

    constexpr int LDS_L0 = 64*(384*2+16) + 2*64*65*4 + 1024*4 + 64*4;   // 87808
    constexpr int LDS_L1 = 64*(768*2+16) + 2*64*65*4 + 1024*4 + 64*4;   // 136960
    hipFuncSetAttribute(reinterpret_cast<const void*>(&rec_kernel<128,true>),
                        hipFuncAttributeMaxDynamicSharedMemorySize, LDS_L0);
    hipFuncSetAttribute(reinterpret_cast<const void*>(&rec_kernel<512,false>),
                        hipFuncAttributeMaxDynamicSharedMemorySize, LDS_L1);

    rec_kernel<128,true><<<32, 512, LDS_L0, stream>>>(x, wih_l0f, whh_l0f, b_l0f,
                                                      wih_l0b, whh_l0b, b_l0b,
                                                      hs0, flags0);
    rec_kernel<512,false><<<32, 512, LDS_L1, stream>>>(hs0, wih_l1f, whh_l1f, b_l1f,
                                                       wih_l1b, whh_l1b, b_l1b,
                                                       hs1, flags1);
    dim3 g88(8, 8, 64);
    sgemm_scores<<<g88, 256, 0, stream>>>(hs1, S);
    softmax_rows<<<8192, 256, 0, stream>>>(S, P);
    transpose_nt<<<g88, 256, 0, stream>>>(hs1, hs1T);
    ctx_gemm<<<g88, 256, 0, stream>>>(P, hs1T, ctx);
    fc1_gemm<<<512, 256, 0, stream>>>(ctx, hs1, fc1wb, fc1b, fc1out);
    bn_stats<<<50, 256, 0, stream>>>(fc1out, stats);
    tail_kernel<<<128, 256, 0, stream>>>(fc1out, stats, bng, bnb, fc2w, fc2b,
                                         fc3w, fc3b, fc4w, fc4b, (float*)d_out);
    (void)in_sizes; (void)n_in; (void)out_size; (void)ws_size;
}